// Round 1
// baseline (698.675 us; speedup 1.0000x reference)
//
#include <hip/hip_runtime.h>
#include <math.h>

#define LOG2PI 1.8378770664093453f
#define F32MIN (-3.4028234663852886e38f)

// ---------------------------------------------------------------------------
// Kernel 1: row sums of squares  lx2[b,t] = sum_c latent^2, lm2[b,s] = sum_c mean^2
// one wave per row
__global__ __launch_bounds__(64) void k_sums(
    const float* __restrict__ latent, const float* __restrict__ mean,
    float* __restrict__ lx2, float* __restrict__ lm2, int BT, int BS, int C) {
  int row = blockIdx.x;
  int lane = threadIdx.x;
  const float* src;
  float* dst;
  if (row < BT) { src = latent + (size_t)row * C; dst = lx2 + row; }
  else          { src = mean + (size_t)(row - BT) * C; dst = lm2 + (row - BT); }
  float s = 0.f;
  for (int c = lane; c < C; c += 64) { float v = src[c]; s += v * v; }
  #pragma unroll
  for (int off = 32; off; off >>= 1) s += __shfl_down(s, off);
  if (lane == 0) *dst = s;
}

// ---------------------------------------------------------------------------
// Kernel 2: ll[b,t,s] = -0.5*(LOG2PI + lx2 - 2*dot + lm2) * attnmask
// 64x64 tiles, 256 threads, 4x4 micro-tile, K staged in LDS (transposed)
__global__ __launch_bounds__(256) void k_scores(
    const float* __restrict__ latent, const float* __restrict__ mean,
    const float* __restrict__ lx2, const float* __restrict__ lm2,
    const int* __restrict__ textlen, const int* __restrict__ mellen,
    float* __restrict__ ll, int T, int S, int C) {
  int b  = blockIdx.z;
  int t0 = blockIdx.x * 64;
  int s0 = blockIdx.y * 64;
  int mel = mellen[b], txt = textlen[b];
  int tid = threadIdx.x;
  int ty = tid >> 4, tx = tid & 15;
  float* out = ll + ((size_t)b * T + t0) * S + s0;

  if (t0 >= mel || s0 >= txt) {
    float4 z = make_float4(0.f, 0.f, 0.f, 0.f);
    #pragma unroll
    for (int i = 0; i < 4; ++i) {
      int tl = ty * 4 + i;
      if (t0 + tl < T) *(float4*)(out + (size_t)tl * S + tx * 4) = z;
    }
    return;
  }

  __shared__ float At[16][64];
  __shared__ float Bt[16][64];
  float acc[4][4] = {};

  const float* Ab = latent + ((size_t)b * T + t0) * C;
  const float* Bb = mean + ((size_t)b * S + s0) * C;

  for (int kk = 0; kk < C; kk += 16) {
    int r  = tid >> 2;
    int cg = tid & 3;
    float4 a = (t0 + r < T) ? *(const float4*)(Ab + (size_t)r * C + kk + cg * 4)
                            : make_float4(0.f, 0.f, 0.f, 0.f);
    float4 bm = *(const float4*)(Bb + (size_t)r * C + kk + cg * 4);
    At[cg * 4 + 0][r] = a.x;  At[cg * 4 + 1][r] = a.y;
    At[cg * 4 + 2][r] = a.z;  At[cg * 4 + 3][r] = a.w;
    Bt[cg * 4 + 0][r] = bm.x; Bt[cg * 4 + 1][r] = bm.y;
    Bt[cg * 4 + 2][r] = bm.z; Bt[cg * 4 + 3][r] = bm.w;
    __syncthreads();
    #pragma unroll
    for (int k = 0; k < 16; ++k) {
      float4 a4 = *(const float4*)&At[k][ty * 4];
      float4 b4 = *(const float4*)&Bt[k][tx * 4];
      float av[4] = {a4.x, a4.y, a4.z, a4.w};
      float bv[4] = {b4.x, b4.y, b4.z, b4.w};
      #pragma unroll
      for (int i = 0; i < 4; ++i)
        #pragma unroll
        for (int j = 0; j < 4; ++j)
          acc[i][j] = fmaf(av[i], bv[j], acc[i][j]);
    }
    __syncthreads();
  }

  #pragma unroll
  for (int i = 0; i < 4; ++i) {
    int t = t0 + ty * 4 + i;
    if (t >= T) continue;
    float lx = lx2[(size_t)b * T + t];
    float4 o;
    float* po = &o.x;
    #pragma unroll
    for (int j = 0; j < 4; ++j) {
      int s = s0 + tx * 4 + j;
      float d = lx - 2.f * acc[i][j] + lm2[(size_t)b * S + s];
      float v = -0.5f * (LOG2PI + d);
      po[j] = (t < mel && s < txt) ? v : 0.f;
    }
    *(float4*)(out + (size_t)(ty * 4 + i) * S + tx * 4) = o;
  }
}

// ---------------------------------------------------------------------------
// Kernel 3: MAS forward scan + backtrack. One wave per batch.
// Lane owns s = lane*6 + k (k=0..5). Direction bits via ballot into LDS.
// Assumes S == 384, T <= 1200.
__global__ __launch_bounds__(64) void k_scan(
    const float* __restrict__ ll, const int* __restrict__ textlen,
    const int* __restrict__ mellen, int* __restrict__ pathidx, int T, int S) {
  int b = blockIdx.x;
  int lane = threadIdx.x;
  __shared__ unsigned long long dir[1200 * 6];

  const float* llb = ll + (size_t)b * T * S;
  int mel = mellen[b], txt = textlen[b];
  int sbase = lane * 6;

  float p0 = 0.f, p1 = 0.f, p2 = 0.f, p3 = 0.f, p4 = 0.f, p5 = 0.f;

#define LOADROW(B_, t_) do { \
    const float2* q_ = (const float2*)(llb + (size_t)(t_) * S + sbase); \
    B_[0] = q_[0]; B_[1] = q_[1]; B_[2] = q_[2]; } while (0)

#define STEP(B_, t_) do { \
    float l0 = B_[0].x, l1 = B_[0].y, l2 = B_[1].x, l3 = B_[1].y, l4 = B_[2].x, l5 = B_[2].y; \
    float up = __shfl_up(p5, 1); \
    float prev0 = (lane == 0) ? -INFINITY : up; \
    bool c0 = p0 >= prev0, c1 = p1 >= p0, c2 = p2 >= p1; \
    bool c3 = p3 >= p2,    c4 = p4 >= p3, c5 = p5 >= p4; \
    float m0 = c0 ? p0 : prev0, m1 = c1 ? p1 : p0, m2 = c2 ? p2 : p1; \
    float m3 = c3 ? p3 : p2,    m4 = c4 ? p4 : p3, m5 = c5 ? p5 : p4; \
    unsigned long long w0 = __ballot(c0), w1 = __ballot(c1), w2 = __ballot(c2); \
    unsigned long long w3 = __ballot(c3), w4 = __ballot(c4), w5 = __ballot(c5); \
    p0 = (sbase + 0 <= (t_)) ? m0 + l0 : F32MIN; \
    p1 = (sbase + 1 <= (t_)) ? m1 + l1 : F32MIN; \
    p2 = (sbase + 2 <= (t_)) ? m2 + l2 : F32MIN; \
    p3 = (sbase + 3 <= (t_)) ? m3 + l3 : F32MIN; \
    p4 = (sbase + 4 <= (t_)) ? m4 + l4 : F32MIN; \
    p5 = (sbase + 5 <= (t_)) ? m5 + l5 : F32MIN; \
    if (lane == 0) { int o_ = (t_) * 6; \
      dir[o_ + 0] = w0; dir[o_ + 1] = w1; dir[o_ + 2] = w2; \
      dir[o_ + 3] = w3; dir[o_ + 4] = w4; dir[o_ + 5] = w5; } \
  } while (0)

  float2 bA[3], bB[3], bC[3], bD[3];
  LOADROW(bA, 0); LOADROW(bB, 1); LOADROW(bC, 2); LOADROW(bD, 3);
  for (int t = 0; t < T; t += 4) {
    STEP(bA, t);     if (t + 4 < T) LOADROW(bA, t + 4);
    STEP(bB, t + 1); if (t + 5 < T) LOADROW(bB, t + 5);
    STEP(bC, t + 2); if (t + 6 < T) LOADROW(bC, t + 6);
    STEP(bD, t + 3); if (t + 7 < T) LOADROW(bD, t + 7);
  }
#undef STEP
#undef LOADROW

  size_t base = (size_t)b * T;
  int k0 = T - mel;  // backtrack rows j >= mel: direction forced to 1, i stays txt-1
  for (int k = lane; k < k0; k += 64) pathidx[base + k] = txt - 1;

  if (lane == 0) {
    int i = txt - 1;
    int j = mel - 1;
    unsigned long long w0 = dir[j * 6 + 0], w1 = dir[j * 6 + 1], w2 = dir[j * 6 + 2];
    unsigned long long w3 = dir[j * 6 + 3], w4 = dir[j * 6 + 4], w5 = dir[j * 6 + 5];
    for (int k = k0; k < T; ++k) {
      pathidx[base + k] = i;
      int jn = j - 1;
      int on = (jn >= 0 ? jn : 0) * 6;
      unsigned long long n0 = dir[on + 0], n1 = dir[on + 1], n2 = dir[on + 2];
      unsigned long long n3 = dir[on + 3], n4 = dir[on + 4], n5 = dir[on + 5];
      int ii = (i < 0) ? i + S : i;  // JAX negative-index wrap on the gather
      int d = 1;
      if (ii < txt) {  // j < mel here; outside attnmask direction is 1
        int li = ii / 6, kk = ii % 6;
        unsigned long long w = (kk == 0) ? w0 : (kk == 1) ? w1 : (kk == 2) ? w2
                               : (kk == 3) ? w3 : (kk == 4) ? w4 : w5;
        d = (int)((w >> li) & 1ull);
      }
      i += d - 1;
      w0 = n0; w1 = n1; w2 = n2; w3 = n3; w4 = n4; w5 = n5;
      j = jn;
    }
  }
}

// ---------------------------------------------------------------------------
// Kernel 4: write attn = one_hot(path) * attnmask (overwrites the ll scratch)
__global__ __launch_bounds__(256) void k_scatter(
    float* __restrict__ attn, const int* __restrict__ pathidx,
    const int* __restrict__ textlen, const int* __restrict__ mellen,
    int B, int T, int S) {
  size_t idx = ((size_t)blockIdx.x * blockDim.x + threadIdx.x) * 4;
  size_t total = (size_t)B * T * S;
  if (idx >= total) return;
  int s = (int)(idx % S);
  size_t row = idx / S;
  int b = (int)(row / T);
  int k = (int)(row % T);
  int pi = pathidx[row];
  int mel = mellen[b], txt = textlen[b];
  float4 o = make_float4(0.f, 0.f, 0.f, 0.f);
  if (k < mel && pi >= 0 && pi < S && pi < txt && pi >= s && pi < s + 4)
    (&o.x)[pi - s] = 1.f;
  *(float4*)(attn + idx) = o;
}

// ---------------------------------------------------------------------------
// Kernel 5: rowsum[b,k] = sum_c (latent - aligned)^2 ; aligned = mean[path] or 0
__global__ __launch_bounds__(256) void k_rowloss(
    const float* __restrict__ latent, const float* __restrict__ mean,
    const int* __restrict__ pathidx, const int* __restrict__ textlen,
    const int* __restrict__ mellen, float* __restrict__ rowsum,
    int T, int S, int C) {
  int row = blockIdx.x * 4 + (threadIdx.x >> 6);
  int lane = threadIdx.x & 63;
  int b = row / T, k = row % T;
  int pi = pathidx[row];
  int mel = mellen[b], txt = textlen[b];
  bool on = (k < mel) && (pi >= 0) && (pi < S) && (pi < txt);
  const float* L = latent + (size_t)row * C;
  const float* M = mean + ((size_t)b * S + (on ? pi : 0)) * C;
  float s = 0.f;
  for (int c = lane; c < C; c += 64) {
    float d = L[c] - (on ? M[c] : 0.f);
    s += d * d;
  }
  #pragma unroll
  for (int off = 32; off; off >>= 1) s += __shfl_down(s, off);
  if (lane == 0) rowsum[row] = s;
}

// ---------------------------------------------------------------------------
// Kernel 6: per-batch durloss (histogram + log) and nll reduction
__global__ __launch_bounds__(256) void k_batch(
    const float* __restrict__ rowsum, const int* __restrict__ pathidx,
    const float* __restrict__ logdur, const int* __restrict__ textlen,
    const int* __restrict__ mellen, float* __restrict__ nllc,
    float* __restrict__ durc, int T, int S, int C) {
  int b = blockIdx.x;
  int tid = threadIdx.x;
  __shared__ int hist[512];
  __shared__ float red[256];
  int mel = mellen[b], txt = textlen[b];
  for (int s = tid; s < S; s += 256) hist[s] = 0;
  __syncthreads();
  for (int k = tid; k < T; k += 256) {
    int pi = pathidx[(size_t)b * T + k];
    if (k < mel && pi >= 0 && pi < S && pi < txt) atomicAdd(&hist[pi], 1);
  }
  __syncthreads();
  float part = 0.f;
  for (int s = tid; s < S; s += 256) {
    float cnt = (float)hist[s];
    float gt = logf(fmaxf(cnt, 1e-5f));
    gt = (s < txt) ? gt : 0.f;
    float d = logdur[(size_t)b * S + s] - gt;
    part += d * d;
  }
  red[tid] = part; __syncthreads();
  #pragma unroll
  for (int off = 128; off; off >>= 1) {
    if (tid < off) red[tid] += red[tid + off];
    __syncthreads();
  }
  if (tid == 0) durc[b] = red[0] / (float)mel;
  __syncthreads();
  part = 0.f;
  for (int k = tid; k < T; k += 256) part += rowsum[(size_t)b * T + k];
  red[tid] = part; __syncthreads();
  #pragma unroll
  for (int off = 128; off; off >>= 1) {
    if (tid < off) red[tid] += red[tid + off];
    __syncthreads();
  }
  if (tid == 0) nllc[b] = 0.5f * (LOG2PI + red[0]) / ((float)mel * (float)C);
}

// ---------------------------------------------------------------------------
// Kernel 7: loss = mean(nllc) + mean(durc)
__global__ __launch_bounds__(64) void k_final(
    const float* __restrict__ nllc, const float* __restrict__ durc,
    float* __restrict__ out, int B) {
  int lane = threadIdx.x;
  float v = (lane < B) ? (nllc[lane] + durc[lane]) : 0.f;
  #pragma unroll
  for (int off = 32; off; off >>= 1) v += __shfl_down(v, off);
  if (lane == 0) out[0] = v / (float)B;
}

// ---------------------------------------------------------------------------
extern "C" void kernel_launch(void* const* d_in, const int* in_sizes, int n_in,
                              void* d_out, int out_size, void* d_ws, size_t ws_size,
                              hipStream_t stream) {
  (void)n_in; (void)out_size; (void)ws_size;
  const float* latent = (const float*)d_in[0];
  const float* mean   = (const float*)d_in[1];
  const float* logdur = (const float*)d_in[2];
  const int*   textlen = (const int*)d_in[3];
  const int*   mellen  = (const int*)d_in[4];

  int B = in_sizes[3];
  int S = in_sizes[2] / B;
  int C = in_sizes[1] / (B * S);
  int T = in_sizes[0] / (B * C);

  float* out = (float*)d_out;
  float* ll = out + 1;  // reuse attn region [B*T*S] as ll scratch, overwritten later

  char* ws = (char*)d_ws;
  float* lx2    = (float*)ws;            // B*T
  float* lm2    = lx2 + (size_t)B * T;   // B*S
  int*   pathidx = (int*)(lm2 + (size_t)B * S);          // B*T
  float* rowsum  = (float*)(pathidx + (size_t)B * T);    // B*T
  float* nllc    = rowsum + (size_t)B * T;               // B
  float* durc    = nllc + B;                             // B

  k_sums<<<B * T + B * S, 64, 0, stream>>>(latent, mean, lx2, lm2, B * T, B * S, C);

  dim3 g2((T + 63) / 64, (S + 63) / 64, B);
  k_scores<<<g2, 256, 0, stream>>>(latent, mean, lx2, lm2, textlen, mellen, ll, T, S, C);

  k_scan<<<B, 64, 0, stream>>>(ll, textlen, mellen, pathidx, T, S);

  size_t total = (size_t)B * T * S;
  k_scatter<<<(int)((total / 4 + 255) / 256), 256, 0, stream>>>(ll, pathidx, textlen, mellen, B, T, S);

  k_rowloss<<<(B * T) / 4, 256, 0, stream>>>(latent, mean, pathidx, textlen, mellen, rowsum, T, S, C);

  k_batch<<<B, 256, 0, stream>>>(rowsum, pathidx, logdur, textlen, mellen, nllc, durc, T, S, C);

  k_final<<<1, 64, 0, stream>>>(nllc, durc, out, B);
}

// Round 2
// 606.819 us; speedup vs baseline: 1.1514x; 1.1514x over previous
//
#include <hip/hip_runtime.h>
#include <math.h>

#define LOG2PI 1.8378770664093453f
#define F32MIN (-3.4028234663852886e38f)

// ---------------------------------------------------------------------------
// Kernel 1: row sums of squares  lx2[b,t] = sum_c latent^2, lm2[b,s] = sum_c mean^2
// one wave per row
__global__ __launch_bounds__(64) void k_sums(
    const float* __restrict__ latent, const float* __restrict__ mean,
    float* __restrict__ lx2, float* __restrict__ lm2, int BT, int BS, int C) {
  int row = blockIdx.x;
  int lane = threadIdx.x;
  const float* src;
  float* dst;
  if (row < BT) { src = latent + (size_t)row * C; dst = lx2 + row; }
  else          { src = mean + (size_t)(row - BT) * C; dst = lm2 + (row - BT); }
  float s = 0.f;
  for (int c = lane; c < C; c += 64) { float v = src[c]; s += v * v; }
  #pragma unroll
  for (int off = 32; off; off >>= 1) s += __shfl_down(s, off);
  if (lane == 0) *dst = s;
}

// ---------------------------------------------------------------------------
// Kernel 2: ll[b,t,s] = -0.5*(LOG2PI + lx2 - 2*dot + lm2) * attnmask
// 64x64 tiles, 256 threads, 4x4 micro-tile, K staged in LDS (transposed)
__global__ __launch_bounds__(256) void k_scores(
    const float* __restrict__ latent, const float* __restrict__ mean,
    const float* __restrict__ lx2, const float* __restrict__ lm2,
    const int* __restrict__ textlen, const int* __restrict__ mellen,
    float* __restrict__ ll, int T, int S, int C) {
  int b  = blockIdx.z;
  int t0 = blockIdx.x * 64;
  int s0 = blockIdx.y * 64;
  int mel = mellen[b], txt = textlen[b];
  int tid = threadIdx.x;
  int ty = tid >> 4, tx = tid & 15;
  float* out = ll + ((size_t)b * T + t0) * S + s0;

  if (t0 >= mel || s0 >= txt) {
    float4 z = make_float4(0.f, 0.f, 0.f, 0.f);
    #pragma unroll
    for (int i = 0; i < 4; ++i) {
      int tl = ty * 4 + i;
      if (t0 + tl < T) *(float4*)(out + (size_t)tl * S + tx * 4) = z;
    }
    return;
  }

  __shared__ float At[16][64];
  __shared__ float Bt[16][64];
  float acc[4][4] = {};

  const float* Ab = latent + ((size_t)b * T + t0) * C;
  const float* Bb = mean + ((size_t)b * S + s0) * C;

  for (int kk = 0; kk < C; kk += 16) {
    int r  = tid >> 2;
    int cg = tid & 3;
    float4 a = (t0 + r < T) ? *(const float4*)(Ab + (size_t)r * C + kk + cg * 4)
                            : make_float4(0.f, 0.f, 0.f, 0.f);
    float4 bm = *(const float4*)(Bb + (size_t)r * C + kk + cg * 4);
    At[cg * 4 + 0][r] = a.x;  At[cg * 4 + 1][r] = a.y;
    At[cg * 4 + 2][r] = a.z;  At[cg * 4 + 3][r] = a.w;
    Bt[cg * 4 + 0][r] = bm.x; Bt[cg * 4 + 1][r] = bm.y;
    Bt[cg * 4 + 2][r] = bm.z; Bt[cg * 4 + 3][r] = bm.w;
    __syncthreads();
    #pragma unroll
    for (int k = 0; k < 16; ++k) {
      float4 a4 = *(const float4*)&At[k][ty * 4];
      float4 b4 = *(const float4*)&Bt[k][tx * 4];
      float av[4] = {a4.x, a4.y, a4.z, a4.w};
      float bv[4] = {b4.x, b4.y, b4.z, b4.w};
      #pragma unroll
      for (int i = 0; i < 4; ++i)
        #pragma unroll
        for (int j = 0; j < 4; ++j)
          acc[i][j] = fmaf(av[i], bv[j], acc[i][j]);
    }
    __syncthreads();
  }

  #pragma unroll
  for (int i = 0; i < 4; ++i) {
    int t = t0 + ty * 4 + i;
    if (t >= T) continue;
    float lx = lx2[(size_t)b * T + t];
    float4 o;
    float* po = &o.x;
    #pragma unroll
    for (int j = 0; j < 4; ++j) {
      int s = s0 + tx * 4 + j;
      float d = lx - 2.f * acc[i][j] + lm2[(size_t)b * S + s];
      float v = -0.5f * (LOG2PI + d);
      po[j] = (t < mel && s < txt) ? v : 0.f;
    }
    *(float4*)(out + (size_t)(ty * 4 + i) * S + tx * 4) = o;
  }
}

// ---------------------------------------------------------------------------
// Kernel 3: MAS forward scan + backtrack. One wave per batch.
// Lane owns s = lane*6 + k (k=0..5). Direction bits via ballot into LDS.
// Forward: 16-row-deep register prefetch (48 outstanding float2 loads/lane)
// to cover ~900-cycle memory latency; serial chain per step is only ~4 VALU ops.
// Backtrack: 6-deep named-buffer LDS prefetch (static indices, no scratch).
// Assumes S == 384, T <= 1200.
__global__ __launch_bounds__(64, 1) void k_scan(
    const float* __restrict__ ll, const int* __restrict__ textlen,
    const int* __restrict__ mellen, int* __restrict__ pathidx, int T, int S) {
  int b = blockIdx.x;
  int lane = threadIdx.x;
  __shared__ unsigned long long dir[1200 * 6];

  const float* llb = ll + (size_t)b * T * S;
  int mel = mellen[b], txt = textlen[b];
  int sbase = lane * 6;

  float p0 = 0.f, p1 = 0.f, p2 = 0.f, p3 = 0.f, p4 = 0.f, p5 = 0.f;

#define LOADROW(B_, t_) do { \
    const float2* q_ = (const float2*)(llb + (size_t)(t_) * S + sbase); \
    B_[0] = q_[0]; B_[1] = q_[1]; B_[2] = q_[2]; } while (0)

#define STEP(B_, t_) do { \
    float l0 = B_[0].x, l1 = B_[0].y, l2 = B_[1].x, l3 = B_[1].y, l4 = B_[2].x, l5 = B_[2].y; \
    float up = __shfl_up(p5, 1); \
    float prev0 = (lane == 0) ? -INFINITY : up; \
    bool c0 = p0 >= prev0, c1 = p1 >= p0, c2 = p2 >= p1; \
    bool c3 = p3 >= p2,    c4 = p4 >= p3, c5 = p5 >= p4; \
    float m0 = c0 ? p0 : prev0, m1 = c1 ? p1 : p0, m2 = c2 ? p2 : p1; \
    float m3 = c3 ? p3 : p2,    m4 = c4 ? p4 : p3, m5 = c5 ? p5 : p4; \
    unsigned long long w0 = __ballot(c0), w1 = __ballot(c1), w2 = __ballot(c2); \
    unsigned long long w3 = __ballot(c3), w4 = __ballot(c4), w5 = __ballot(c5); \
    p0 = (sbase + 0 <= (t_)) ? m0 + l0 : F32MIN; \
    p1 = (sbase + 1 <= (t_)) ? m1 + l1 : F32MIN; \
    p2 = (sbase + 2 <= (t_)) ? m2 + l2 : F32MIN; \
    p3 = (sbase + 3 <= (t_)) ? m3 + l3 : F32MIN; \
    p4 = (sbase + 4 <= (t_)) ? m4 + l4 : F32MIN; \
    p5 = (sbase + 5 <= (t_)) ? m5 + l5 : F32MIN; \
    if (lane == 0) { int o_ = (t_) * 6; \
      dir[o_ + 0] = w0; dir[o_ + 1] = w1; dir[o_ + 2] = w2; \
      dir[o_ + 3] = w3; dir[o_ + 4] = w4; dir[o_ + 5] = w5; } \
  } while (0)

  float2 buf[16][3];
  #pragma unroll
  for (int u = 0; u < 16; ++u) LOADROW(buf[u], u);

  int t = 0;
  for (; t + 16 <= T; t += 16) {
    #pragma unroll
    for (int u = 0; u < 16; ++u) {
      STEP(buf[u], t + u);
      if (t + u + 16 < T) LOADROW(buf[u], t + u + 16);
    }
  }
  #pragma unroll
  for (int u = 0; u < 16; ++u) {
    if (t + u < T) STEP(buf[u], t + u);
  }
#undef STEP
#undef LOADROW

  size_t base = (size_t)b * T;
  int k0 = T - mel;  // backtrack rows j >= mel: direction forced to 1, i stays txt-1
  for (int k = lane; k < k0; k += 64) pathidx[base + k] = txt - 1;

  if (lane == 0) {
    int i = txt - 1;
    int j = mel - 1;

#define BTLOAD(RB_, J_) do { int lj_ = (J_) >= 0 ? (J_) : 0; \
    const unsigned long long* pr_ = &dir[lj_ * 6]; \
    RB_[0] = pr_[0]; RB_[1] = pr_[1]; RB_[2] = pr_[2]; \
    RB_[3] = pr_[3]; RB_[4] = pr_[4]; RB_[5] = pr_[5]; } while (0)

#define BTSTEP(RB_, LOADJ_) do { \
    pathidx[base + k] = i; \
    int ii_ = (i < 0) ? i + S : i;  /* JAX negative-index wrap on the gather */ \
    int d_ = 1; \
    if (ii_ < txt) {  /* inside attnmask -> use recorded direction */ \
      int li_ = ii_ / 6, kk_ = ii_ % 6; \
      unsigned long long w_ = (kk_ == 0) ? RB_[0] : (kk_ == 1) ? RB_[1] : (kk_ == 2) ? RB_[2] \
                              : (kk_ == 3) ? RB_[3] : (kk_ == 4) ? RB_[4] : RB_[5]; \
      d_ = (int)((w_ >> li_) & 1ull); \
    } \
    i += d_ - 1; \
    BTLOAD(RB_, LOADJ_); \
    ++k; \
  } while (0)

    unsigned long long rbA[6], rbB[6], rbC[6], rbD[6], rbE[6], rbF[6];
    BTLOAD(rbA, j);     BTLOAD(rbB, j - 1); BTLOAD(rbC, j - 2);
    BTLOAD(rbD, j - 3); BTLOAD(rbE, j - 4); BTLOAD(rbF, j - 5);

    int k = k0;
    while (k + 5 < T) {
      BTSTEP(rbA, j - 6);
      BTSTEP(rbB, j - 7);
      BTSTEP(rbC, j - 8);
      BTSTEP(rbD, j - 9);
      BTSTEP(rbE, j - 10);
      BTSTEP(rbF, j - 11);
      j -= 6;
    }
    if (k < T) BTSTEP(rbA, 0);
    if (k < T) BTSTEP(rbB, 0);
    if (k < T) BTSTEP(rbC, 0);
    if (k < T) BTSTEP(rbD, 0);
    if (k < T) BTSTEP(rbE, 0);
#undef BTSTEP
#undef BTLOAD
  }
}

// ---------------------------------------------------------------------------
// Kernel 4: write attn = one_hot(path) * attnmask (overwrites the ll scratch)
__global__ __launch_bounds__(256) void k_scatter(
    float* __restrict__ attn, const int* __restrict__ pathidx,
    const int* __restrict__ textlen, const int* __restrict__ mellen,
    int B, int T, int S) {
  size_t idx = ((size_t)blockIdx.x * blockDim.x + threadIdx.x) * 4;
  size_t total = (size_t)B * T * S;
  if (idx >= total) return;
  int s = (int)(idx % S);
  size_t row = idx / S;
  int b = (int)(row / T);
  int k = (int)(row % T);
  int pi = pathidx[row];
  int mel = mellen[b], txt = textlen[b];
  float4 o = make_float4(0.f, 0.f, 0.f, 0.f);
  if (k < mel && pi >= 0 && pi < S && pi < txt && pi >= s && pi < s + 4)
    (&o.x)[pi - s] = 1.f;
  *(float4*)(attn + idx) = o;
}

// ---------------------------------------------------------------------------
// Kernel 5: rowsum[b,k] = sum_c (latent - aligned)^2 ; aligned = mean[path] or 0
__global__ __launch_bounds__(256) void k_rowloss(
    const float* __restrict__ latent, const float* __restrict__ mean,
    const int* __restrict__ pathidx, const int* __restrict__ textlen,
    const int* __restrict__ mellen, float* __restrict__ rowsum,
    int T, int S, int C) {
  int row = blockIdx.x * 4 + (threadIdx.x >> 6);
  int lane = threadIdx.x & 63;
  int b = row / T, k = row % T;
  int pi = pathidx[row];
  int mel = mellen[b], txt = textlen[b];
  bool on = (k < mel) && (pi >= 0) && (pi < S) && (pi < txt);
  const float* L = latent + (size_t)row * C;
  const float* M = mean + ((size_t)b * S + (on ? pi : 0)) * C;
  float s = 0.f;
  for (int c = lane; c < C; c += 64) {
    float d = L[c] - (on ? M[c] : 0.f);
    s += d * d;
  }
  #pragma unroll
  for (int off = 32; off; off >>= 1) s += __shfl_down(s, off);
  if (lane == 0) rowsum[row] = s;
}

// ---------------------------------------------------------------------------
// Kernel 6: per-batch durloss (histogram + log) and nll reduction
__global__ __launch_bounds__(256) void k_batch(
    const float* __restrict__ rowsum, const int* __restrict__ pathidx,
    const float* __restrict__ logdur, const int* __restrict__ textlen,
    const int* __restrict__ mellen, float* __restrict__ nllc,
    float* __restrict__ durc, int T, int S, int C) {
  int b = blockIdx.x;
  int tid = threadIdx.x;
  __shared__ int hist[512];
  __shared__ float red[256];
  int mel = mellen[b], txt = textlen[b];
  for (int s = tid; s < S; s += 256) hist[s] = 0;
  __syncthreads();
  for (int k = tid; k < T; k += 256) {
    int pi = pathidx[(size_t)b * T + k];
    if (k < mel && pi >= 0 && pi < S && pi < txt) atomicAdd(&hist[pi], 1);
  }
  __syncthreads();
  float part = 0.f;
  for (int s = tid; s < S; s += 256) {
    float cnt = (float)hist[s];
    float gt = logf(fmaxf(cnt, 1e-5f));
    gt = (s < txt) ? gt : 0.f;
    float d = logdur[(size_t)b * S + s] - gt;
    part += d * d;
  }
  red[tid] = part; __syncthreads();
  #pragma unroll
  for (int off = 128; off; off >>= 1) {
    if (tid < off) red[tid] += red[tid + off];
    __syncthreads();
  }
  if (tid == 0) durc[b] = red[0] / (float)mel;
  __syncthreads();
  part = 0.f;
  for (int k = tid; k < T; k += 256) part += rowsum[(size_t)b * T + k];
  red[tid] = part; __syncthreads();
  #pragma unroll
  for (int off = 128; off; off >>= 1) {
    if (tid < off) red[tid] += red[tid + off];
    __syncthreads();
  }
  if (tid == 0) nllc[b] = 0.5f * (LOG2PI + red[0]) / ((float)mel * (float)C);
}

// ---------------------------------------------------------------------------
// Kernel 7: loss = mean(nllc) + mean(durc)
__global__ __launch_bounds__(64) void k_final(
    const float* __restrict__ nllc, const float* __restrict__ durc,
    float* __restrict__ out, int B) {
  int lane = threadIdx.x;
  float v = (lane < B) ? (nllc[lane] + durc[lane]) : 0.f;
  #pragma unroll
  for (int off = 32; off; off >>= 1) v += __shfl_down(v, off);
  if (lane == 0) out[0] = v / (float)B;
}

// ---------------------------------------------------------------------------
extern "C" void kernel_launch(void* const* d_in, const int* in_sizes, int n_in,
                              void* d_out, int out_size, void* d_ws, size_t ws_size,
                              hipStream_t stream) {
  (void)n_in; (void)out_size; (void)ws_size;
  const float* latent = (const float*)d_in[0];
  const float* mean   = (const float*)d_in[1];
  const float* logdur = (const float*)d_in[2];
  const int*   textlen = (const int*)d_in[3];
  const int*   mellen  = (const int*)d_in[4];

  int B = in_sizes[3];
  int S = in_sizes[2] / B;
  int C = in_sizes[1] / (B * S);
  int T = in_sizes[0] / (B * C);

  float* out = (float*)d_out;
  float* ll = out + 1;  // reuse attn region [B*T*S] as ll scratch, overwritten later

  char* ws = (char*)d_ws;
  float* lx2    = (float*)ws;            // B*T
  float* lm2    = lx2 + (size_t)B * T;   // B*S
  int*   pathidx = (int*)(lm2 + (size_t)B * S);          // B*T
  float* rowsum  = (float*)(pathidx + (size_t)B * T);    // B*T
  float* nllc    = rowsum + (size_t)B * T;               // B
  float* durc    = nllc + B;                             // B

  k_sums<<<B * T + B * S, 64, 0, stream>>>(latent, mean, lx2, lm2, B * T, B * S, C);

  dim3 g2((T + 63) / 64, (S + 63) / 64, B);
  k_scores<<<g2, 256, 0, stream>>>(latent, mean, lx2, lm2, textlen, mellen, ll, T, S, C);

  k_scan<<<B, 64, 0, stream>>>(ll, textlen, mellen, pathidx, T, S);

  size_t total = (size_t)B * T * S;
  k_scatter<<<(int)((total / 4 + 255) / 256), 256, 0, stream>>>(ll, pathidx, textlen, mellen, B, T, S);

  k_rowloss<<<(B * T) / 4, 256, 0, stream>>>(latent, mean, pathidx, textlen, mellen, rowsum, T, S, C);

  k_batch<<<B, 256, 0, stream>>>(rowsum, pathidx, logdur, textlen, mellen, nllc, durc, T, S, C);

  k_final<<<1, 64, 0, stream>>>(nllc, durc, out, B);
}

// Round 3
// 546.819 us; speedup vs baseline: 1.2777x; 1.1097x over previous
//
#include <hip/hip_runtime.h>
#include <math.h>

#define LOG2PI 1.8378770664093453f
#define F32MIN (-3.4028234663852886e38f)

// ---------------------------------------------------------------------------
// Kernel 1: row sums of squares  lx2[b,t] = sum_c latent^2, lm2[b,s] = sum_c mean^2
// one wave per row
__global__ __launch_bounds__(64) void k_sums(
    const float* __restrict__ latent, const float* __restrict__ mean,
    float* __restrict__ lx2, float* __restrict__ lm2, int BT, int BS, int C) {
  int row = blockIdx.x;
  int lane = threadIdx.x;
  const float* src;
  float* dst;
  if (row < BT) { src = latent + (size_t)row * C; dst = lx2 + row; }
  else          { src = mean + (size_t)(row - BT) * C; dst = lm2 + (row - BT); }
  float s = 0.f;
  for (int c = lane; c < C; c += 64) { float v = src[c]; s += v * v; }
  #pragma unroll
  for (int off = 32; off; off >>= 1) s += __shfl_down(s, off);
  if (lane == 0) *dst = s;
}

// ---------------------------------------------------------------------------
// Kernel 2: ll[b,t,s] = -0.5*(LOG2PI + lx2 - 2*dot + lm2) * attnmask
// 64x64 tiles, 256 threads, 4x4 micro-tile, K staged in LDS (transposed)
__global__ __launch_bounds__(256) void k_scores(
    const float* __restrict__ latent, const float* __restrict__ mean,
    const float* __restrict__ lx2, const float* __restrict__ lm2,
    const int* __restrict__ textlen, const int* __restrict__ mellen,
    float* __restrict__ ll, int T, int S, int C) {
  int b  = blockIdx.z;
  int t0 = blockIdx.x * 64;
  int s0 = blockIdx.y * 64;
  int mel = mellen[b], txt = textlen[b];
  int tid = threadIdx.x;
  int ty = tid >> 4, tx = tid & 15;
  float* out = ll + ((size_t)b * T + t0) * S + s0;

  if (t0 >= mel || s0 >= txt) {
    float4 z = make_float4(0.f, 0.f, 0.f, 0.f);
    #pragma unroll
    for (int i = 0; i < 4; ++i) {
      int tl = ty * 4 + i;
      if (t0 + tl < T) *(float4*)(out + (size_t)tl * S + tx * 4) = z;
    }
    return;
  }

  __shared__ float At[16][64];
  __shared__ float Bt[16][64];
  float acc[4][4] = {};

  const float* Ab = latent + ((size_t)b * T + t0) * C;
  const float* Bb = mean + ((size_t)b * S + s0) * C;

  for (int kk = 0; kk < C; kk += 16) {
    int r  = tid >> 2;
    int cg = tid & 3;
    float4 a = (t0 + r < T) ? *(const float4*)(Ab + (size_t)r * C + kk + cg * 4)
                            : make_float4(0.f, 0.f, 0.f, 0.f);
    float4 bm = *(const float4*)(Bb + (size_t)r * C + kk + cg * 4);
    At[cg * 4 + 0][r] = a.x;  At[cg * 4 + 1][r] = a.y;
    At[cg * 4 + 2][r] = a.z;  At[cg * 4 + 3][r] = a.w;
    Bt[cg * 4 + 0][r] = bm.x; Bt[cg * 4 + 1][r] = bm.y;
    Bt[cg * 4 + 2][r] = bm.z; Bt[cg * 4 + 3][r] = bm.w;
    __syncthreads();
    #pragma unroll
    for (int k = 0; k < 16; ++k) {
      float4 a4 = *(const float4*)&At[k][ty * 4];
      float4 b4 = *(const float4*)&Bt[k][tx * 4];
      float av[4] = {a4.x, a4.y, a4.z, a4.w};
      float bv[4] = {b4.x, b4.y, b4.z, b4.w};
      #pragma unroll
      for (int i = 0; i < 4; ++i)
        #pragma unroll
        for (int j = 0; j < 4; ++j)
          acc[i][j] = fmaf(av[i], bv[j], acc[i][j]);
    }
    __syncthreads();
  }

  #pragma unroll
  for (int i = 0; i < 4; ++i) {
    int t = t0 + ty * 4 + i;
    if (t >= T) continue;
    float lx = lx2[(size_t)b * T + t];
    float4 o;
    float* po = &o.x;
    #pragma unroll
    for (int j = 0; j < 4; ++j) {
      int s = s0 + tx * 4 + j;
      float d = lx - 2.f * acc[i][j] + lm2[(size_t)b * S + s];
      float v = -0.5f * (LOG2PI + d);
      po[j] = (t < mel && s < txt) ? v : 0.f;
    }
    *(float4*)(out + (size_t)(ty * 4 + i) * S + tx * 4) = o;
  }
}

// ---------------------------------------------------------------------------
// Kernel 3: MAS forward scan + backtrack. One wave per batch.
// Lane owns s = lane*6 + k (k=0..5). Direction bits via ballot into LDS.
// Forward: 16-row-deep register prefetch. Hot loop loads are UNCONDITIONAL
// (t+32<=T guarantees in-bounds) so the compiler can emit counted
// s_waitcnt vmcnt(45) instead of a conservative vmcnt(0) drain — conditional
// loads make the outstanding count unknowable and serialize every step at
// full memory latency (the R2 bug).
// Backtrack: 6-deep named-buffer LDS prefetch (static indices).
// Assumes S == 384, T <= 1200.
__global__ __launch_bounds__(64, 1) void k_scan(
    const float* __restrict__ ll, const int* __restrict__ textlen,
    const int* __restrict__ mellen, int* __restrict__ pathidx, int T, int S) {
  int b = blockIdx.x;
  int lane = threadIdx.x;
  __shared__ unsigned long long dir[1200 * 6];

  const float* llb = ll + (size_t)b * T * S;
  int mel = mellen[b], txt = textlen[b];
  int sbase = lane * 6;

  float p0 = 0.f, p1 = 0.f, p2 = 0.f, p3 = 0.f, p4 = 0.f, p5 = 0.f;

#define LOADROW(B_, t_) do { \
    const float2* q_ = (const float2*)(llb + (size_t)(t_) * S + sbase); \
    B_[0] = q_[0]; B_[1] = q_[1]; B_[2] = q_[2]; } while (0)

#define STEP(B_, t_) do { \
    float l0 = B_[0].x, l1 = B_[0].y, l2 = B_[1].x, l3 = B_[1].y, l4 = B_[2].x, l5 = B_[2].y; \
    float up = __shfl_up(p5, 1); \
    float prev0 = (lane == 0) ? -INFINITY : up; \
    bool c0 = p0 >= prev0, c1 = p1 >= p0, c2 = p2 >= p1; \
    bool c3 = p3 >= p2,    c4 = p4 >= p3, c5 = p5 >= p4; \
    float m0 = c0 ? p0 : prev0, m1 = c1 ? p1 : p0, m2 = c2 ? p2 : p1; \
    float m3 = c3 ? p3 : p2,    m4 = c4 ? p4 : p3, m5 = c5 ? p5 : p4; \
    unsigned long long w0 = __ballot(c0), w1 = __ballot(c1), w2 = __ballot(c2); \
    unsigned long long w3 = __ballot(c3), w4 = __ballot(c4), w5 = __ballot(c5); \
    p0 = (sbase + 0 <= (t_)) ? m0 + l0 : F32MIN; \
    p1 = (sbase + 1 <= (t_)) ? m1 + l1 : F32MIN; \
    p2 = (sbase + 2 <= (t_)) ? m2 + l2 : F32MIN; \
    p3 = (sbase + 3 <= (t_)) ? m3 + l3 : F32MIN; \
    p4 = (sbase + 4 <= (t_)) ? m4 + l4 : F32MIN; \
    p5 = (sbase + 5 <= (t_)) ? m5 + l5 : F32MIN; \
    if (lane == 0) { int o_ = (t_) * 6; \
      dir[o_ + 0] = w0; dir[o_ + 1] = w1; dir[o_ + 2] = w2; \
      dir[o_ + 3] = w3; dir[o_ + 4] = w4; dir[o_ + 5] = w5; } \
  } while (0)

  float2 buf[16][3];
  #pragma unroll
  for (int u = 0; u < 16; ++u) LOADROW(buf[u], u);

  int t = 0;
  // Hot loop: loads are unconditional -> counted vmcnt, 48 loads in flight.
  for (; t + 32 <= T; t += 16) {
    #pragma unroll
    for (int u = 0; u < 16; ++u) {
      STEP(buf[u], t + u);
      LOADROW(buf[u], t + u + 16);
    }
  }
  // Penultimate block (runs at most once): conditional prefetch.
  for (; t + 16 <= T; t += 16) {
    #pragma unroll
    for (int u = 0; u < 16; ++u) {
      STEP(buf[u], t + u);
      if (t + u + 16 < T) LOADROW(buf[u], t + u + 16);
    }
  }
  // Tail: no loads.
  #pragma unroll
  for (int u = 0; u < 16; ++u) {
    if (t + u < T) STEP(buf[u], t + u);
  }
#undef STEP
#undef LOADROW

  size_t base = (size_t)b * T;
  int k0 = T - mel;  // backtrack rows j >= mel: direction forced to 1, i stays txt-1
  for (int k = lane; k < k0; k += 64) pathidx[base + k] = txt - 1;

  if (lane == 0) {
    int i = txt - 1;
    int j = mel - 1;

#define BTLOAD(RB_, J_) do { int lj_ = (J_) >= 0 ? (J_) : 0; \
    const unsigned long long* pr_ = &dir[lj_ * 6]; \
    RB_[0] = pr_[0]; RB_[1] = pr_[1]; RB_[2] = pr_[2]; \
    RB_[3] = pr_[3]; RB_[4] = pr_[4]; RB_[5] = pr_[5]; } while (0)

#define BTSTEP(RB_, LOADJ_) do { \
    pathidx[base + k] = i; \
    int ii_ = (i < 0) ? i + S : i;  /* JAX negative-index wrap on the gather */ \
    int d_ = 1; \
    if (ii_ < txt) {  /* inside attnmask -> use recorded direction */ \
      int li_ = ii_ / 6, kk_ = ii_ % 6; \
      unsigned long long w_ = (kk_ == 0) ? RB_[0] : (kk_ == 1) ? RB_[1] : (kk_ == 2) ? RB_[2] \
                              : (kk_ == 3) ? RB_[3] : (kk_ == 4) ? RB_[4] : RB_[5]; \
      d_ = (int)((w_ >> li_) & 1ull); \
    } \
    i += d_ - 1; \
    BTLOAD(RB_, LOADJ_); \
    ++k; \
  } while (0)

    unsigned long long rbA[6], rbB[6], rbC[6], rbD[6], rbE[6], rbF[6];
    BTLOAD(rbA, j);     BTLOAD(rbB, j - 1); BTLOAD(rbC, j - 2);
    BTLOAD(rbD, j - 3); BTLOAD(rbE, j - 4); BTLOAD(rbF, j - 5);

    int k = k0;
    while (k + 5 < T) {
      BTSTEP(rbA, j - 6);
      BTSTEP(rbB, j - 7);
      BTSTEP(rbC, j - 8);
      BTSTEP(rbD, j - 9);
      BTSTEP(rbE, j - 10);
      BTSTEP(rbF, j - 11);
      j -= 6;
    }
    if (k < T) BTSTEP(rbA, 0);
    if (k < T) BTSTEP(rbB, 0);
    if (k < T) BTSTEP(rbC, 0);
    if (k < T) BTSTEP(rbD, 0);
    if (k < T) BTSTEP(rbE, 0);
#undef BTSTEP
#undef BTLOAD
  }
}

// ---------------------------------------------------------------------------
// Kernel 4: write attn = one_hot(path) * attnmask (overwrites the ll scratch)
__global__ __launch_bounds__(256) void k_scatter(
    float* __restrict__ attn, const int* __restrict__ pathidx,
    const int* __restrict__ textlen, const int* __restrict__ mellen,
    int B, int T, int S) {
  size_t idx = ((size_t)blockIdx.x * blockDim.x + threadIdx.x) * 4;
  size_t total = (size_t)B * T * S;
  if (idx >= total) return;
  int s = (int)(idx % S);
  size_t row = idx / S;
  int b = (int)(row / T);
  int k = (int)(row % T);
  int pi = pathidx[row];
  int mel = mellen[b], txt = textlen[b];
  float4 o = make_float4(0.f, 0.f, 0.f, 0.f);
  if (k < mel && pi >= 0 && pi < S && pi < txt && pi >= s && pi < s + 4)
    (&o.x)[pi - s] = 1.f;
  *(float4*)(attn + idx) = o;
}

// ---------------------------------------------------------------------------
// Kernel 5: rowsum[b,k] = sum_c (latent - aligned)^2 ; aligned = mean[path] or 0
__global__ __launch_bounds__(256) void k_rowloss(
    const float* __restrict__ latent, const float* __restrict__ mean,
    const int* __restrict__ pathidx, const int* __restrict__ textlen,
    const int* __restrict__ mellen, float* __restrict__ rowsum,
    int T, int S, int C) {
  int row = blockIdx.x * 4 + (threadIdx.x >> 6);
  int lane = threadIdx.x & 63;
  int b = row / T, k = row % T;
  int pi = pathidx[row];
  int mel = mellen[b], txt = textlen[b];
  bool on = (k < mel) && (pi >= 0) && (pi < S) && (pi < txt);
  const float* L = latent + (size_t)row * C;
  const float* M = mean + ((size_t)b * S + (on ? pi : 0)) * C;
  float s = 0.f;
  for (int c = lane; c < C; c += 64) {
    float d = L[c] - (on ? M[c] : 0.f);
    s += d * d;
  }
  #pragma unroll
  for (int off = 32; off; off >>= 1) s += __shfl_down(s, off);
  if (lane == 0) rowsum[row] = s;
}

// ---------------------------------------------------------------------------
// Kernel 6: per-batch durloss (histogram + log) and nll reduction
__global__ __launch_bounds__(256) void k_batch(
    const float* __restrict__ rowsum, const int* __restrict__ pathidx,
    const float* __restrict__ logdur, const int* __restrict__ textlen,
    const int* __restrict__ mellen, float* __restrict__ nllc,
    float* __restrict__ durc, int T, int S, int C) {
  int b = blockIdx.x;
  int tid = threadIdx.x;
  __shared__ int hist[512];
  __shared__ float red[256];
  int mel = mellen[b], txt = textlen[b];
  for (int s = tid; s < S; s += 256) hist[s] = 0;
  __syncthreads();
  for (int k = tid; k < T; k += 256) {
    int pi = pathidx[(size_t)b * T + k];
    if (k < mel && pi >= 0 && pi < S && pi < txt) atomicAdd(&hist[pi], 1);
  }
  __syncthreads();
  float part = 0.f;
  for (int s = tid; s < S; s += 256) {
    float cnt = (float)hist[s];
    float gt = logf(fmaxf(cnt, 1e-5f));
    gt = (s < txt) ? gt : 0.f;
    float d = logdur[(size_t)b * S + s] - gt;
    part += d * d;
  }
  red[tid] = part; __syncthreads();
  #pragma unroll
  for (int off = 128; off; off >>= 1) {
    if (tid < off) red[tid] += red[tid + off];
    __syncthreads();
  }
  if (tid == 0) durc[b] = red[0] / (float)mel;
  __syncthreads();
  part = 0.f;
  for (int k = tid; k < T; k += 256) part += rowsum[(size_t)b * T + k];
  red[tid] = part; __syncthreads();
  #pragma unroll
  for (int off = 128; off; off >>= 1) {
    if (tid < off) red[tid] += red[tid + off];
    __syncthreads();
  }
  if (tid == 0) nllc[b] = 0.5f * (LOG2PI + red[0]) / ((float)mel * (float)C);
}

// ---------------------------------------------------------------------------
// Kernel 7: loss = mean(nllc) + mean(durc)
__global__ __launch_bounds__(64) void k_final(
    const float* __restrict__ nllc, const float* __restrict__ durc,
    float* __restrict__ out, int B) {
  int lane = threadIdx.x;
  float v = (lane < B) ? (nllc[lane] + durc[lane]) : 0.f;
  #pragma unroll
  for (int off = 32; off; off >>= 1) v += __shfl_down(v, off);
  if (lane == 0) out[0] = v / (float)B;
}

// ---------------------------------------------------------------------------
extern "C" void kernel_launch(void* const* d_in, const int* in_sizes, int n_in,
                              void* d_out, int out_size, void* d_ws, size_t ws_size,
                              hipStream_t stream) {
  (void)n_in; (void)out_size; (void)ws_size;
  const float* latent = (const float*)d_in[0];
  const float* mean   = (const float*)d_in[1];
  const float* logdur = (const float*)d_in[2];
  const int*   textlen = (const int*)d_in[3];
  const int*   mellen  = (const int*)d_in[4];

  int B = in_sizes[3];
  int S = in_sizes[2] / B;
  int C = in_sizes[1] / (B * S);
  int T = in_sizes[0] / (B * C);

  float* out = (float*)d_out;
  float* ll = out + 1;  // reuse attn region [B*T*S] as ll scratch, overwritten later

  char* ws = (char*)d_ws;
  float* lx2    = (float*)ws;            // B*T
  float* lm2    = lx2 + (size_t)B * T;   // B*S
  int*   pathidx = (int*)(lm2 + (size_t)B * S);          // B*T
  float* rowsum  = (float*)(pathidx + (size_t)B * T);    // B*T
  float* nllc    = rowsum + (size_t)B * T;               // B
  float* durc    = nllc + B;                             // B

  k_sums<<<B * T + B * S, 64, 0, stream>>>(latent, mean, lx2, lm2, B * T, B * S, C);

  dim3 g2((T + 63) / 64, (S + 63) / 64, B);
  k_scores<<<g2, 256, 0, stream>>>(latent, mean, lx2, lm2, textlen, mellen, ll, T, S, C);

  k_scan<<<B, 64, 0, stream>>>(ll, textlen, mellen, pathidx, T, S);

  size_t total = (size_t)B * T * S;
  k_scatter<<<(int)((total / 4 + 255) / 256), 256, 0, stream>>>(ll, pathidx, textlen, mellen, B, T, S);

  k_rowloss<<<(B * T) / 4, 256, 0, stream>>>(latent, mean, pathidx, textlen, mellen, rowsum, T, S, C);

  k_batch<<<B, 256, 0, stream>>>(rowsum, pathidx, logdur, textlen, mellen, nllc, durc, T, S, C);

  k_final<<<1, 64, 0, stream>>>(nllc, durc, out, B);
}

// Round 4
// 525.192 us; speedup vs baseline: 1.3303x; 1.0412x over previous
//
#include <hip/hip_runtime.h>
#include <math.h>

#define LOG2PI 1.8378770664093453f
#define F32MIN (-3.4028234663852886e38f)
#define CH 30          // ll rows per LDS chunk
#define SMAX 384       // S (lane math assumes 384 = 64 lanes * 6 cols)
#define TMAX 1200

// ---------------------------------------------------------------------------
// Kernel 1: row sums of squares  lx2[b,t] = sum_c latent^2, lm2[b,s] = sum_c mean^2
__global__ __launch_bounds__(64) void k_sums(
    const float* __restrict__ latent, const float* __restrict__ mean,
    float* __restrict__ lx2, float* __restrict__ lm2, int BT, int BS, int C) {
  int row = blockIdx.x;
  int lane = threadIdx.x;
  const float* src;
  float* dst;
  if (row < BT) { src = latent + (size_t)row * C; dst = lx2 + row; }
  else          { src = mean + (size_t)(row - BT) * C; dst = lm2 + (row - BT); }
  float s = 0.f;
  for (int c = lane; c < C; c += 64) { float v = src[c]; s += v * v; }
  #pragma unroll
  for (int off = 32; off; off >>= 1) s += __shfl_down(s, off);
  if (lane == 0) *dst = s;
}

// ---------------------------------------------------------------------------
// Kernel 2: ll[b,t,s] = -0.5*(LOG2PI + lx2 - 2*dot + lm2) * attnmask
__global__ __launch_bounds__(256) void k_scores(
    const float* __restrict__ latent, const float* __restrict__ mean,
    const float* __restrict__ lx2, const float* __restrict__ lm2,
    const int* __restrict__ textlen, const int* __restrict__ mellen,
    float* __restrict__ ll, int T, int S, int C) {
  int b  = blockIdx.z;
  int t0 = blockIdx.x * 64;
  int s0 = blockIdx.y * 64;
  int mel = mellen[b], txt = textlen[b];
  int tid = threadIdx.x;
  int ty = tid >> 4, tx = tid & 15;
  float* out = ll + ((size_t)b * T + t0) * S + s0;

  if (t0 >= mel || s0 >= txt) {
    float4 z = make_float4(0.f, 0.f, 0.f, 0.f);
    #pragma unroll
    for (int i = 0; i < 4; ++i) {
      int tl = ty * 4 + i;
      if (t0 + tl < T) *(float4*)(out + (size_t)tl * S + tx * 4) = z;
    }
    return;
  }

  __shared__ float At[16][64];
  __shared__ float Bt[16][64];
  float acc[4][4] = {};

  const float* Ab = latent + ((size_t)b * T + t0) * C;
  const float* Bb = mean + ((size_t)b * S + s0) * C;

  for (int kk = 0; kk < C; kk += 16) {
    int r  = tid >> 2;
    int cg = tid & 3;
    float4 a = (t0 + r < T) ? *(const float4*)(Ab + (size_t)r * C + kk + cg * 4)
                            : make_float4(0.f, 0.f, 0.f, 0.f);
    float4 bm = *(const float4*)(Bb + (size_t)r * C + kk + cg * 4);
    At[cg * 4 + 0][r] = a.x;  At[cg * 4 + 1][r] = a.y;
    At[cg * 4 + 2][r] = a.z;  At[cg * 4 + 3][r] = a.w;
    Bt[cg * 4 + 0][r] = bm.x; Bt[cg * 4 + 1][r] = bm.y;
    Bt[cg * 4 + 2][r] = bm.z; Bt[cg * 4 + 3][r] = bm.w;
    __syncthreads();
    #pragma unroll
    for (int k = 0; k < 16; ++k) {
      float4 a4 = *(const float4*)&At[k][ty * 4];
      float4 b4 = *(const float4*)&Bt[k][tx * 4];
      float av[4] = {a4.x, a4.y, a4.z, a4.w};
      float bv[4] = {b4.x, b4.y, b4.z, b4.w};
      #pragma unroll
      for (int i = 0; i < 4; ++i)
        #pragma unroll
        for (int j = 0; j < 4; ++j)
          acc[i][j] = fmaf(av[i], bv[j], acc[i][j]);
    }
    __syncthreads();
  }

  #pragma unroll
  for (int i = 0; i < 4; ++i) {
    int t = t0 + ty * 4 + i;
    if (t >= T) continue;
    float lx = lx2[(size_t)b * T + t];
    float4 o;
    float* po = &o.x;
    #pragma unroll
    for (int j = 0; j < 4; ++j) {
      int s = s0 + tx * 4 + j;
      float d = lx - 2.f * acc[i][j] + lm2[(size_t)b * S + s];
      float v = -0.5f * (LOG2PI + d);
      po[j] = (t < mel && s < txt) ? v : 0.f;
    }
    *(float4*)(out + (size_t)(ty * 4 + i) * S + tx * 4) = o;
  }
}

// ---------------------------------------------------------------------------
// MAS scan chunk: wave 0 only, CH rows from LDS. 4-slot register prefetch
// ring (static indices). MASKED variant applies the x_range<=t gating
// (only needed while t < S+6).
template <bool MASKED>
__device__ __forceinline__ void scan_chunk(
    const float (*__restrict__ rcur)[SMAX], int t0, int lane, int sbase,
    float& p0, float& p1, float& p2, float& p3, float& p4, float& p5,
    unsigned long long* dir) {
  float2 rb[4][3];
#define RLOAD(SL_, r_) do { \
    const float2* q_ = (const float2*)&rcur[r_][sbase]; \
    rb[SL_][0] = q_[0]; rb[SL_][1] = q_[1]; rb[SL_][2] = q_[2]; } while (0)
  RLOAD(0, 0); RLOAD(1, 1); RLOAD(2, 2); RLOAD(3, 3);
  #pragma unroll
  for (int r = 0; r < CH; ++r) {
    int t = t0 + r;
    float l0 = rb[r & 3][0].x, l1 = rb[r & 3][0].y, l2 = rb[r & 3][1].x;
    float l3 = rb[r & 3][1].y, l4 = rb[r & 3][2].x, l5 = rb[r & 3][2].y;
    float up = __shfl_up(p5, 1);
    float prev0 = (lane == 0) ? -INFINITY : up;
    bool c0 = p0 >= prev0, c1 = p1 >= p0, c2 = p2 >= p1;
    bool c3 = p3 >= p2,    c4 = p4 >= p3, c5 = p5 >= p4;
    float m0 = c0 ? p0 : prev0, m1 = c1 ? p1 : p0, m2 = c2 ? p2 : p1;
    float m3 = c3 ? p3 : p2,    m4 = c4 ? p4 : p3, m5 = c5 ? p5 : p4;
    unsigned long long w0 = __ballot(c0), w1 = __ballot(c1), w2 = __ballot(c2);
    unsigned long long w3 = __ballot(c3), w4 = __ballot(c4), w5 = __ballot(c5);
    if (MASKED) {
      p0 = (sbase + 0 <= t) ? m0 + l0 : F32MIN;
      p1 = (sbase + 1 <= t) ? m1 + l1 : F32MIN;
      p2 = (sbase + 2 <= t) ? m2 + l2 : F32MIN;
      p3 = (sbase + 3 <= t) ? m3 + l3 : F32MIN;
      p4 = (sbase + 4 <= t) ? m4 + l4 : F32MIN;
      p5 = (sbase + 5 <= t) ? m5 + l5 : F32MIN;
    } else {
      p0 = m0 + l0; p1 = m1 + l1; p2 = m2 + l2;
      p3 = m3 + l3; p4 = m4 + l4; p5 = m5 + l5;
    }
    if (r < CH - 4) RLOAD(r & 3, r + 4);
    if (lane == 0) {
      int o = t * 6;
      dir[o + 0] = w0; dir[o + 1] = w1; dir[o + 2] = w2;
      dir[o + 3] = w3; dir[o + 4] = w4; dir[o + 5] = w5;
    }
  }
#undef RLOAD
}

// ---------------------------------------------------------------------------
// Kernel 3: MAS forward scan + backtrack. One block (4 waves) per batch.
// Wave 0: scan recurrence, pure LDS+VALU (NO vmcnt waits in its stream).
// Waves 1-3: double-buffer the next 30-row ll chunk global->reg->LDS;
// their (conservative) vmcnt waits are private to their waves, and the
// ~900cy load latency hides under wave 0's ~2700cy chunk scan.
__global__ __launch_bounds__(256, 1) void k_scan(
    const float* __restrict__ ll, const int* __restrict__ textlen,
    const int* __restrict__ mellen, int* __restrict__ pathidx, int T, int S) {
  int b = blockIdx.x;
  int tid = threadIdx.x;
  int lane = tid & 63;
  __shared__ float rows[2][CH][SMAX];            // 92160 B
  __shared__ unsigned long long dir[TMAX * 6];   // 57600 B

  const float* llb = ll + (size_t)b * T * S;
  int mel = mellen[b], txt = textlen[b];
  int nch = T / CH;
  int sbase = lane * 6;
  float p0 = 0.f, p1 = 0.f, p2 = 0.f, p3 = 0.f, p4 = 0.f, p5 = 0.f;

  // prologue: loader threads fill chunk 0 (CH*S*4 = 46080 B = 2880 float4,
  // 192 loaders x 15 each)
  if (tid >= 64) {
    int lid = tid - 64;
    const float4* gsrc = (const float4*)llb;
    float4* ldst = (float4*)&rows[0][0][0];
    #pragma unroll
    for (int k = 0; k < 15; ++k) ldst[k * 192 + lid] = gsrc[k * 192 + lid];
  }
  __syncthreads();

  for (int c = 0; c < nch; ++c) {
    if (tid >= 64) {
      if (c + 1 < nch) {
        int lid = tid - 64;
        const float4* gsrc = (const float4*)(llb + (size_t)(c + 1) * CH * S);
        float4 stg[15];
        #pragma unroll
        for (int k = 0; k < 15; ++k) stg[k] = gsrc[k * 192 + lid];
        float4* ldst = (float4*)&rows[(c + 1) & 1][0][0];
        #pragma unroll
        for (int k = 0; k < 15; ++k) ldst[k * 192 + lid] = stg[k];
      }
    } else {
      int t0 = c * CH;
      if (t0 < S + 6)
        scan_chunk<true >(rows[c & 1], t0, lane, sbase, p0, p1, p2, p3, p4, p5, dir);
      else
        scan_chunk<false>(rows[c & 1], t0, lane, sbase, p0, p1, p2, p3, p4, p5, dir);
    }
    __syncthreads();
  }

  if (tid >= 64) return;

  // generic tail if T % CH != 0 (not taken for T=1200): scan from global
  for (int t = nch * CH; t < T; ++t) {
    const float2* q = (const float2*)(llb + (size_t)t * S + sbase);
    float2 qa = q[0], qb = q[1], qc = q[2];
    float up = __shfl_up(p5, 1);
    float prev0 = (lane == 0) ? -INFINITY : up;
    bool c0 = p0 >= prev0, c1 = p1 >= p0, c2 = p2 >= p1;
    bool c3 = p3 >= p2,    c4 = p4 >= p3, c5 = p5 >= p4;
    float m0 = c0 ? p0 : prev0, m1 = c1 ? p1 : p0, m2 = c2 ? p2 : p1;
    float m3 = c3 ? p3 : p2,    m4 = c4 ? p4 : p3, m5 = c5 ? p5 : p4;
    unsigned long long w0 = __ballot(c0), w1 = __ballot(c1), w2 = __ballot(c2);
    unsigned long long w3 = __ballot(c3), w4 = __ballot(c4), w5 = __ballot(c5);
    p0 = (sbase + 0 <= t) ? m0 + qa.x : F32MIN;
    p1 = (sbase + 1 <= t) ? m1 + qa.y : F32MIN;
    p2 = (sbase + 2 <= t) ? m2 + qb.x : F32MIN;
    p3 = (sbase + 3 <= t) ? m3 + qb.y : F32MIN;
    p4 = (sbase + 4 <= t) ? m4 + qc.x : F32MIN;
    p5 = (sbase + 5 <= t) ? m5 + qc.y : F32MIN;
    if (lane == 0) {
      int o = t * 6;
      dir[o + 0] = w0; dir[o + 1] = w1; dir[o + 2] = w2;
      dir[o + 3] = w3; dir[o + 4] = w4; dir[o + 5] = w5;
    }
  }

  size_t base = (size_t)b * T;
  int k0 = T - mel;  // backtrack rows j >= mel: direction forced to 1
  for (int k = lane; k < k0; k += 64) pathidx[base + k] = txt - 1;

  if (lane == 0) {
    int i = txt - 1;
    int j = mel - 1;

#define BTLOAD(RB_, J_) do { int lj_ = (J_) >= 0 ? (J_) : 0; \
    const unsigned long long* pr_ = &dir[lj_ * 6]; \
    RB_[0] = pr_[0]; RB_[1] = pr_[1]; RB_[2] = pr_[2]; \
    RB_[3] = pr_[3]; RB_[4] = pr_[4]; RB_[5] = pr_[5]; } while (0)

#define BTSTEP(RB_, LOADJ_) do { \
    pathidx[base + k] = i; \
    int ii_ = (i < 0) ? i + S : i;  /* JAX negative-index wrap on the gather */ \
    int d_ = 1; \
    if (ii_ < txt) {  /* inside attnmask -> use recorded direction */ \
      int li_ = ii_ / 6, kk_ = ii_ % 6; \
      unsigned long long w_ = (kk_ == 0) ? RB_[0] : (kk_ == 1) ? RB_[1] : (kk_ == 2) ? RB_[2] \
                              : (kk_ == 3) ? RB_[3] : (kk_ == 4) ? RB_[4] : RB_[5]; \
      d_ = (int)((w_ >> li_) & 1ull); \
    } \
    i += d_ - 1; \
    BTLOAD(RB_, LOADJ_); \
    ++k; \
  } while (0)

    unsigned long long rbA[6], rbB[6], rbC[6], rbD[6], rbE[6], rbF[6];
    BTLOAD(rbA, j);     BTLOAD(rbB, j - 1); BTLOAD(rbC, j - 2);
    BTLOAD(rbD, j - 3); BTLOAD(rbE, j - 4); BTLOAD(rbF, j - 5);

    int k = k0;
    while (k + 5 < T) {
      BTSTEP(rbA, j - 6);
      BTSTEP(rbB, j - 7);
      BTSTEP(rbC, j - 8);
      BTSTEP(rbD, j - 9);
      BTSTEP(rbE, j - 10);
      BTSTEP(rbF, j - 11);
      j -= 6;
    }
    if (k < T) BTSTEP(rbA, 0);
    if (k < T) BTSTEP(rbB, 0);
    if (k < T) BTSTEP(rbC, 0);
    if (k < T) BTSTEP(rbD, 0);
    if (k < T) BTSTEP(rbE, 0);
#undef BTSTEP
#undef BTLOAD
  }
}

// ---------------------------------------------------------------------------
// Kernel 4: write attn = one_hot(path) * attnmask (overwrites the ll scratch)
__global__ __launch_bounds__(256) void k_scatter(
    float* __restrict__ attn, const int* __restrict__ pathidx,
    const int* __restrict__ textlen, const int* __restrict__ mellen,
    int B, int T, int S) {
  size_t idx = ((size_t)blockIdx.x * blockDim.x + threadIdx.x) * 4;
  size_t total = (size_t)B * T * S;
  if (idx >= total) return;
  int s = (int)(idx % S);
  size_t row = idx / S;
  int b = (int)(row / T);
  int k = (int)(row % T);
  int pi = pathidx[row];
  int mel = mellen[b], txt = textlen[b];
  float4 o = make_float4(0.f, 0.f, 0.f, 0.f);
  if (k < mel && pi >= 0 && pi < S && pi < txt && pi >= s && pi < s + 4)
    (&o.x)[pi - s] = 1.f;
  *(float4*)(attn + idx) = o;
}

// ---------------------------------------------------------------------------
// Kernel 5: rowsum[b,k] = sum_c (latent - aligned)^2 ; aligned = mean[path] or 0
__global__ __launch_bounds__(256) void k_rowloss(
    const float* __restrict__ latent, const float* __restrict__ mean,
    const int* __restrict__ pathidx, const int* __restrict__ textlen,
    const int* __restrict__ mellen, float* __restrict__ rowsum,
    int T, int S, int C) {
  int row = blockIdx.x * 4 + (threadIdx.x >> 6);
  int lane = threadIdx.x & 63;
  int b = row / T, k = row % T;
  int pi = pathidx[row];
  int mel = mellen[b], txt = textlen[b];
  bool on = (k < mel) && (pi >= 0) && (pi < S) && (pi < txt);
  const float* L = latent + (size_t)row * C;
  const float* M = mean + ((size_t)b * S + (on ? pi : 0)) * C;
  float s = 0.f;
  for (int c = lane; c < C; c += 64) {
    float d = L[c] - (on ? M[c] : 0.f);
    s += d * d;
  }
  #pragma unroll
  for (int off = 32; off; off >>= 1) s += __shfl_down(s, off);
  if (lane == 0) rowsum[row] = s;
}

// ---------------------------------------------------------------------------
// Kernel 6: per-batch durloss (histogram + log) and nll reduction
__global__ __launch_bounds__(256) void k_batch(
    const float* __restrict__ rowsum, const int* __restrict__ pathidx,
    const float* __restrict__ logdur, const int* __restrict__ textlen,
    const int* __restrict__ mellen, float* __restrict__ nllc,
    float* __restrict__ durc, int T, int S, int C) {
  int b = blockIdx.x;
  int tid = threadIdx.x;
  __shared__ int hist[512];
  __shared__ float red[256];
  int mel = mellen[b], txt = textlen[b];
  for (int s = tid; s < S; s += 256) hist[s] = 0;
  __syncthreads();
  for (int k = tid; k < T; k += 256) {
    int pi = pathidx[(size_t)b * T + k];
    if (k < mel && pi >= 0 && pi < S && pi < txt) atomicAdd(&hist[pi], 1);
  }
  __syncthreads();
  float part = 0.f;
  for (int s = tid; s < S; s += 256) {
    float cnt = (float)hist[s];
    float gt = logf(fmaxf(cnt, 1e-5f));
    gt = (s < txt) ? gt : 0.f;
    float d = logdur[(size_t)b * S + s] - gt;
    part += d * d;
  }
  red[tid] = part; __syncthreads();
  #pragma unroll
  for (int off = 128; off; off >>= 1) {
    if (tid < off) red[tid] += red[tid + off];
    __syncthreads();
  }
  if (tid == 0) durc[b] = red[0] / (float)mel;
  __syncthreads();
  part = 0.f;
  for (int k = tid; k < T; k += 256) part += rowsum[(size_t)b * T + k];
  red[tid] = part; __syncthreads();
  #pragma unroll
  for (int off = 128; off; off >>= 1) {
    if (tid < off) red[tid] += red[tid + off];
    __syncthreads();
  }
  if (tid == 0) nllc[b] = 0.5f * (LOG2PI + red[0]) / ((float)mel * (float)C);
}

// ---------------------------------------------------------------------------
// Kernel 7: loss = mean(nllc) + mean(durc)
__global__ __launch_bounds__(64) void k_final(
    const float* __restrict__ nllc, const float* __restrict__ durc,
    float* __restrict__ out, int B) {
  int lane = threadIdx.x;
  float v = (lane < B) ? (nllc[lane] + durc[lane]) : 0.f;
  #pragma unroll
  for (int off = 32; off; off >>= 1) v += __shfl_down(v, off);
  if (lane == 0) out[0] = v / (float)B;
}

// ---------------------------------------------------------------------------
extern "C" void kernel_launch(void* const* d_in, const int* in_sizes, int n_in,
                              void* d_out, int out_size, void* d_ws, size_t ws_size,
                              hipStream_t stream) {
  (void)n_in; (void)out_size; (void)ws_size;
  const float* latent = (const float*)d_in[0];
  const float* mean   = (const float*)d_in[1];
  const float* logdur = (const float*)d_in[2];
  const int*   textlen = (const int*)d_in[3];
  const int*   mellen  = (const int*)d_in[4];

  int B = in_sizes[3];
  int S = in_sizes[2] / B;
  int C = in_sizes[1] / (B * S);
  int T = in_sizes[0] / (B * C);

  float* out = (float*)d_out;
  float* ll = out + 1;  // reuse attn region [B*T*S] as ll scratch, overwritten later

  char* ws = (char*)d_ws;
  float* lx2    = (float*)ws;            // B*T
  float* lm2    = lx2 + (size_t)B * T;   // B*S
  int*   pathidx = (int*)(lm2 + (size_t)B * S);          // B*T
  float* rowsum  = (float*)(pathidx + (size_t)B * T);    // B*T
  float* nllc    = rowsum + (size_t)B * T;               // B
  float* durc    = nllc + B;                             // B

  k_sums<<<B * T + B * S, 64, 0, stream>>>(latent, mean, lx2, lm2, B * T, B * S, C);

  dim3 g2((T + 63) / 64, (S + 63) / 64, B);
  k_scores<<<g2, 256, 0, stream>>>(latent, mean, lx2, lm2, textlen, mellen, ll, T, S, C);

  k_scan<<<B, 256, 0, stream>>>(ll, textlen, mellen, pathidx, T, S);

  size_t total = (size_t)B * T * S;
  k_scatter<<<(int)((total / 4 + 255) / 256), 256, 0, stream>>>(ll, pathidx, textlen, mellen, B, T, S);

  k_rowloss<<<(B * T) / 4, 256, 0, stream>>>(latent, mean, pathidx, textlen, mellen, rowsum, T, S, C);

  k_batch<<<B, 256, 0, stream>>>(rowsum, pathidx, logdur, textlen, mellen, nllc, durc, T, S, C);

  k_final<<<1, 64, 0, stream>>>(nllc, durc, out, B);
}

// Round 5
// 377.625 us; speedup vs baseline: 1.8502x; 1.3908x over previous
//
#include <hip/hip_runtime.h>
#include <math.h>

#define LOG2PI 1.8378770664093453f
#define F32MIN (-3.4028234663852886e38f)
#define CH 32          // ll rows per LDS chunk (= direction word size)
#define SMAX 384       // S (lane math assumes 384 = 64 lanes * 6 cols)
#define NW 38          // direction words per column = ceil(1200/32)

// ---------------------------------------------------------------------------
// Kernel 1: row sums of squares  lx2[b,t] = sum_c latent^2, lm2[b,s] = sum_c mean^2
__global__ __launch_bounds__(64) void k_sums(
    const float* __restrict__ latent, const float* __restrict__ mean,
    float* __restrict__ lx2, float* __restrict__ lm2, int BT, int BS, int C) {
  int row = blockIdx.x;
  int lane = threadIdx.x;
  const float* src;
  float* dst;
  if (row < BT) { src = latent + (size_t)row * C; dst = lx2 + row; }
  else          { src = mean + (size_t)(row - BT) * C; dst = lm2 + (row - BT); }
  float s = 0.f;
  for (int c = lane; c < C; c += 64) { float v = src[c]; s += v * v; }
  #pragma unroll
  for (int off = 32; off; off >>= 1) s += __shfl_down(s, off);
  if (lane == 0) *dst = s;
}

// ---------------------------------------------------------------------------
// Kernel 2: ll[b,t,s] = -0.5*(LOG2PI + lx2 - 2*dot + lm2) * attnmask
__global__ __launch_bounds__(256) void k_scores(
    const float* __restrict__ latent, const float* __restrict__ mean,
    const float* __restrict__ lx2, const float* __restrict__ lm2,
    const int* __restrict__ textlen, const int* __restrict__ mellen,
    float* __restrict__ ll, int T, int S, int C) {
  int b  = blockIdx.z;
  int t0 = blockIdx.x * 64;
  int s0 = blockIdx.y * 64;
  int mel = mellen[b], txt = textlen[b];
  int tid = threadIdx.x;
  int ty = tid >> 4, tx = tid & 15;
  float* out = ll + ((size_t)b * T + t0) * S + s0;

  if (t0 >= mel || s0 >= txt) {
    float4 z = make_float4(0.f, 0.f, 0.f, 0.f);
    #pragma unroll
    for (int i = 0; i < 4; ++i) {
      int tl = ty * 4 + i;
      if (t0 + tl < T) *(float4*)(out + (size_t)tl * S + tx * 4) = z;
    }
    return;
  }

  __shared__ float At[16][64];
  __shared__ float Bt[16][64];
  float acc[4][4] = {};

  const float* Ab = latent + ((size_t)b * T + t0) * C;
  const float* Bb = mean + ((size_t)b * S + s0) * C;

  for (int kk = 0; kk < C; kk += 16) {
    int r  = tid >> 2;
    int cg = tid & 3;
    float4 a = (t0 + r < T) ? *(const float4*)(Ab + (size_t)r * C + kk + cg * 4)
                            : make_float4(0.f, 0.f, 0.f, 0.f);
    float4 bm = *(const float4*)(Bb + (size_t)r * C + kk + cg * 4);
    At[cg * 4 + 0][r] = a.x;  At[cg * 4 + 1][r] = a.y;
    At[cg * 4 + 2][r] = a.z;  At[cg * 4 + 3][r] = a.w;
    Bt[cg * 4 + 0][r] = bm.x; Bt[cg * 4 + 1][r] = bm.y;
    Bt[cg * 4 + 2][r] = bm.z; Bt[cg * 4 + 3][r] = bm.w;
    __syncthreads();
    #pragma unroll
    for (int k = 0; k < 16; ++k) {
      float4 a4 = *(const float4*)&At[k][ty * 4];
      float4 b4 = *(const float4*)&Bt[k][tx * 4];
      float av[4] = {a4.x, a4.y, a4.z, a4.w};
      float bv[4] = {b4.x, b4.y, b4.z, b4.w};
      #pragma unroll
      for (int i = 0; i < 4; ++i)
        #pragma unroll
        for (int j = 0; j < 4; ++j)
          acc[i][j] = fmaf(av[i], bv[j], acc[i][j]);
    }
    __syncthreads();
  }

  #pragma unroll
  for (int i = 0; i < 4; ++i) {
    int t = t0 + ty * 4 + i;
    if (t >= T) continue;
    float lx = lx2[(size_t)b * T + t];
    float4 o;
    float* po = &o.x;
    #pragma unroll
    for (int j = 0; j < 4; ++j) {
      int s = s0 + tx * 4 + j;
      float d = lx - 2.f * acc[i][j] + lm2[(size_t)b * S + s];
      float v = -0.5f * (LOG2PI + d);
      po[j] = (t < mel && s < txt) ? v : 0.f;
    }
    *(float4*)(out + (size_t)(ty * 4 + i) * S + tx * 4) = o;
  }
}

// ---------------------------------------------------------------------------
// DPP wave_shr:1 — lane l gets lane l-1's value, lane 0 gets -inf.
// Pure VALU (no LDS / lgkmcnt), unlike __shfl_up (ds_permute).
__device__ __forceinline__ float dpp_shr1_neginf(float x) {
  int r = __builtin_amdgcn_update_dpp(
      __float_as_int(-INFINITY), __float_as_int(x),
      0x138 /*wave_shr:1*/, 0xf, 0xf, false);
  return __int_as_float(r);
}

// ---------------------------------------------------------------------------
// MAS scan chunk (wave 0): ROWS steps from LDS. Per step: 1 DPP + ~30 VALU +
// 3 ds_read_b64 (4-deep ring, the ONLY lgkm ops in flight -> counted waits).
// Direction bits packed per-lane per-column into u32 accumulators; ONE
// 6-word flush per chunk (no ballots, no lane0 branch, no per-step writes).
template <bool MASKED, int ROWS>
__device__ __forceinline__ void scan_chunk(
    const float* __restrict__ rcur, int t0, int sbase,
    float& p0, float& p1, float& p2, float& p3, float& p4, float& p5,
    unsigned* __restrict__ dirT, int cw) {
  unsigned a0 = 0, a1 = 0, a2 = 0, a3 = 0, a4 = 0, a5 = 0;
  float2 rb[4][3];
  const float2* q0 = (const float2*)(rcur + sbase);
  #pragma unroll
  for (int u = 0; u < 4; ++u) {
    rb[u][0] = q0[u * 192]; rb[u][1] = q0[u * 192 + 1]; rb[u][2] = q0[u * 192 + 2];
  }
  #pragma unroll
  for (int r = 0; r < ROWS; ++r) {
    float l0 = rb[r & 3][0].x, l1 = rb[r & 3][0].y, l2 = rb[r & 3][1].x;
    float l3 = rb[r & 3][1].y, l4 = rb[r & 3][2].x, l5 = rb[r & 3][2].y;
    float pm1 = dpp_shr1_neginf(p5);
    bool c0 = p0 >= pm1, c1 = p1 >= p0, c2 = p2 >= p1;
    bool c3 = p3 >= p2,  c4 = p4 >= p3, c5 = p5 >= p4;
    float m0 = c0 ? p0 : pm1, m1 = c1 ? p1 : p0, m2 = c2 ? p2 : p1;
    float m3 = c3 ? p3 : p2,  m4 = c4 ? p4 : p3, m5 = c5 ? p5 : p4;
    a0 |= (unsigned)c0 << r; a1 |= (unsigned)c1 << r; a2 |= (unsigned)c2 << r;
    a3 |= (unsigned)c3 << r; a4 |= (unsigned)c4 << r; a5 |= (unsigned)c5 << r;
    if (MASKED) {
      int t = t0 + r;
      p0 = (sbase + 0 <= t) ? m0 + l0 : F32MIN;
      p1 = (sbase + 1 <= t) ? m1 + l1 : F32MIN;
      p2 = (sbase + 2 <= t) ? m2 + l2 : F32MIN;
      p3 = (sbase + 3 <= t) ? m3 + l3 : F32MIN;
      p4 = (sbase + 4 <= t) ? m4 + l4 : F32MIN;
      p5 = (sbase + 5 <= t) ? m5 + l5 : F32MIN;
    } else {
      p0 = m0 + l0; p1 = m1 + l1; p2 = m2 + l2;
      p3 = m3 + l3; p4 = m4 + l4; p5 = m5 + l5;
    }
    if (r + 4 < ROWS) {
      const float2* qn = q0 + (r + 4) * 192;
      rb[r & 3][0] = qn[0]; rb[r & 3][1] = qn[1]; rb[r & 3][2] = qn[2];
    }
  }
  unsigned* dcol = dirT + (unsigned)sbase * NW + cw;
  dcol[0 * NW] = a0; dcol[1 * NW] = a1; dcol[2 * NW] = a2;
  dcol[3 * NW] = a3; dcol[4 * NW] = a4; dcol[5 * NW] = a5;
}

// ---------------------------------------------------------------------------
// Kernel 3: MAS forward scan + backtrack. One block (4 waves) per batch.
// Wave 0: scan recurrence (LDS reads only). Waves 1-3: double-buffer the next
// 32-row ll chunk global->reg->LDS. Assumes S == 384, T == 37*32 + 16.
__global__ __launch_bounds__(256, 1) void k_scan(
    const float* __restrict__ ll, const int* __restrict__ textlen,
    const int* __restrict__ mellen, int* __restrict__ pathidx, int T, int S) {
  int b = blockIdx.x;
  int tid = threadIdx.x;
  int lane = tid & 63;
  __shared__ float rows[2][CH][SMAX];       // 98304 B
  __shared__ unsigned dirT[SMAX * NW];      // 58368 B (column-major bit-pack)

  const float* llb = ll + (size_t)b * T * S;
  int mel = mellen[b], txt = textlen[b];
  int sbase = lane * 6;
  int nfull = T / CH;                        // 37
  int nch = (T + CH - 1) / CH;               // 38 (16-row tail)
  float p0 = 0.f, p1 = 0.f, p2 = 0.f, p3 = 0.f, p4 = 0.f, p5 = 0.f;

  // prologue: loader waves fill chunk 0 (32*384 floats = 3072 float4, 192x16)
  if (tid >= 64) {
    int lid = tid - 64;
    const float4* g = (const float4*)llb;
    float4* d = (float4*)&rows[0][0][0];
    #pragma unroll
    for (int k = 0; k < 16; ++k) d[k * 192 + lid] = g[k * 192 + lid];
  }
  __syncthreads();

  for (int c = 0; c < nch; ++c) {
    if (tid >= 64) {
      int nxt = c + 1;
      if (nxt < nch) {
        int lid = tid - 64;
        const float4* g = (const float4*)(llb + (size_t)nxt * CH * S);
        float4* d = (float4*)&rows[nxt & 1][0][0];
        if (nxt < nfull) {
          float4 stg[16];
          #pragma unroll
          for (int k = 0; k < 16; ++k) stg[k] = g[k * 192 + lid];
          #pragma unroll
          for (int k = 0; k < 16; ++k) d[k * 192 + lid] = stg[k];
        } else {
          float4 stg[8];
          #pragma unroll
          for (int k = 0; k < 8; ++k) stg[k] = g[k * 192 + lid];
          #pragma unroll
          for (int k = 0; k < 8; ++k) d[k * 192 + lid] = stg[k];
        }
      }
    } else {
      const float* rc = &rows[c & 1][0][0];
      int t0 = c * CH;
      if (c < nfull) {
        if (t0 + CH - 1 < S)   // any row in chunk may still need s<=t masking
          scan_chunk<true, CH>(rc, t0, sbase, p0, p1, p2, p3, p4, p5, dirT, c);
        else
          scan_chunk<false, CH>(rc, t0, sbase, p0, p1, p2, p3, p4, p5, dirT, c);
      } else {
        scan_chunk<false, 16>(rc, t0, sbase, p0, p1, p2, p3, p4, p5, dirT, c);
      }
    }
    __syncthreads();
  }

  if (tid >= 64) return;

  size_t base = (size_t)b * T;
  int k0 = T - mel;  // rows j >= mel: direction forced to 1, i stays txt-1
  for (int k = lane; k < k0; k += 64) pathidx[base + k] = txt - 1;

  if (lane == 0) {
    // Backtrack on column-major words. Reload the cached word only when the
    // path changes column (d==0) or crosses a 32-row word boundary.
    int i = txt - 1;
    int j = mel - 1;
    unsigned w = ~0u;
    bool reload = true;
    for (int k = k0; k < T; ++k) {
      pathidx[base + k] = i;
      if (reload) {
        int ii = (i < 0) ? i + S : i;   // JAX negative-index wrap
        ii = (ii < 0) ? 0 : ii;         // JAX clamp below -S
        w = (ii < txt) ? dirT[ii * NW + (j >> 5)] : ~0u;  // outside mask: d=1
      }
      int d = (int)((w >> (j & 31)) & 1u);
      reload = (d == 0) | ((j & 31) == 0);
      i += d - 1;
      --j;
    }
  }
}

// ---------------------------------------------------------------------------
// Kernel 4: write attn = one_hot(path) * attnmask (overwrites the ll scratch)
__global__ __launch_bounds__(256) void k_scatter(
    float* __restrict__ attn, const int* __restrict__ pathidx,
    const int* __restrict__ textlen, const int* __restrict__ mellen,
    int B, int T, int S) {
  size_t idx = ((size_t)blockIdx.x * blockDim.x + threadIdx.x) * 4;
  size_t total = (size_t)B * T * S;
  if (idx >= total) return;
  int s = (int)(idx % S);
  size_t row = idx / S;
  int b = (int)(row / T);
  int k = (int)(row % T);
  int pi = pathidx[row];
  int mel = mellen[b], txt = textlen[b];
  float4 o = make_float4(0.f, 0.f, 0.f, 0.f);
  if (k < mel && pi >= 0 && pi < S && pi < txt && pi >= s && pi < s + 4)
    (&o.x)[pi - s] = 1.f;
  *(float4*)(attn + idx) = o;
}

// ---------------------------------------------------------------------------
// Kernel 5: rowsum[b,k] = sum_c (latent - aligned)^2 ; aligned = mean[path] or 0
__global__ __launch_bounds__(256) void k_rowloss(
    const float* __restrict__ latent, const float* __restrict__ mean,
    const int* __restrict__ pathidx, const int* __restrict__ textlen,
    const int* __restrict__ mellen, float* __restrict__ rowsum,
    int T, int S, int C) {
  int row = blockIdx.x * 4 + (threadIdx.x >> 6);
  int lane = threadIdx.x & 63;
  int b = row / T, k = row % T;
  int pi = pathidx[row];
  int mel = mellen[b], txt = textlen[b];
  bool on = (k < mel) && (pi >= 0) && (pi < S) && (pi < txt);
  const float* L = latent + (size_t)row * C;
  const float* M = mean + ((size_t)b * S + (on ? pi : 0)) * C;
  float s = 0.f;
  for (int c = lane; c < C; c += 64) {
    float d = L[c] - (on ? M[c] : 0.f);
    s += d * d;
  }
  #pragma unroll
  for (int off = 32; off; off >>= 1) s += __shfl_down(s, off);
  if (lane == 0) rowsum[row] = s;
}

// ---------------------------------------------------------------------------
// Kernel 6: per-batch durloss (histogram + log) and nll reduction
__global__ __launch_bounds__(256) void k_batch(
    const float* __restrict__ rowsum, const int* __restrict__ pathidx,
    const float* __restrict__ logdur, const int* __restrict__ textlen,
    const int* __restrict__ mellen, float* __restrict__ nllc,
    float* __restrict__ durc, int T, int S, int C) {
  int b = blockIdx.x;
  int tid = threadIdx.x;
  __shared__ int hist[512];
  __shared__ float red[256];
  int mel = mellen[b], txt = textlen[b];
  for (int s = tid; s < S; s += 256) hist[s] = 0;
  __syncthreads();
  for (int k = tid; k < T; k += 256) {
    int pi = pathidx[(size_t)b * T + k];
    if (k < mel && pi >= 0 && pi < S && pi < txt) atomicAdd(&hist[pi], 1);
  }
  __syncthreads();
  float part = 0.f;
  for (int s = tid; s < S; s += 256) {
    float cnt = (float)hist[s];
    float gt = logf(fmaxf(cnt, 1e-5f));
    gt = (s < txt) ? gt : 0.f;
    float d = logdur[(size_t)b * S + s] - gt;
    part += d * d;
  }
  red[tid] = part; __syncthreads();
  #pragma unroll
  for (int off = 128; off; off >>= 1) {
    if (tid < off) red[tid] += red[tid + off];
    __syncthreads();
  }
  if (tid == 0) durc[b] = red[0] / (float)mel;
  __syncthreads();
  part = 0.f;
  for (int k = tid; k < T; k += 256) part += rowsum[(size_t)b * T + k];
  red[tid] = part; __syncthreads();
  #pragma unroll
  for (int off = 128; off; off >>= 1) {
    if (tid < off) red[tid] += red[tid + off];
    __syncthreads();
  }
  if (tid == 0) nllc[b] = 0.5f * (LOG2PI + red[0]) / ((float)mel * (float)C);
}

// ---------------------------------------------------------------------------
// Kernel 7: loss = mean(nllc) + mean(durc)
__global__ __launch_bounds__(64) void k_final(
    const float* __restrict__ nllc, const float* __restrict__ durc,
    float* __restrict__ out, int B) {
  int lane = threadIdx.x;
  float v = (lane < B) ? (nllc[lane] + durc[lane]) : 0.f;
  #pragma unroll
  for (int off = 32; off; off >>= 1) v += __shfl_down(v, off);
  if (lane == 0) out[0] = v / (float)B;
}

// ---------------------------------------------------------------------------
extern "C" void kernel_launch(void* const* d_in, const int* in_sizes, int n_in,
                              void* d_out, int out_size, void* d_ws, size_t ws_size,
                              hipStream_t stream) {
  (void)n_in; (void)out_size; (void)ws_size;
  const float* latent = (const float*)d_in[0];
  const float* mean   = (const float*)d_in[1];
  const float* logdur = (const float*)d_in[2];
  const int*   textlen = (const int*)d_in[3];
  const int*   mellen  = (const int*)d_in[4];

  int B = in_sizes[3];
  int S = in_sizes[2] / B;
  int C = in_sizes[1] / (B * S);
  int T = in_sizes[0] / (B * C);

  float* out = (float*)d_out;
  float* ll = out + 1;  // reuse attn region [B*T*S] as ll scratch, overwritten later

  char* ws = (char*)d_ws;
  float* lx2    = (float*)ws;            // B*T
  float* lm2    = lx2 + (size_t)B * T;   // B*S
  int*   pathidx = (int*)(lm2 + (size_t)B * S);          // B*T
  float* rowsum  = (float*)(pathidx + (size_t)B * T);    // B*T
  float* nllc    = rowsum + (size_t)B * T;               // B
  float* durc    = nllc + B;                             // B

  k_sums<<<B * T + B * S, 64, 0, stream>>>(latent, mean, lx2, lm2, B * T, B * S, C);

  dim3 g2((T + 63) / 64, (S + 63) / 64, B);
  k_scores<<<g2, 256, 0, stream>>>(latent, mean, lx2, lm2, textlen, mellen, ll, T, S, C);

  k_scan<<<B, 256, 0, stream>>>(ll, textlen, mellen, pathidx, T, S);

  size_t total = (size_t)B * T * S;
  k_scatter<<<(int)((total / 4 + 255) / 256), 256, 0, stream>>>(ll, pathidx, textlen, mellen, B, T, S);

  k_rowloss<<<(B * T) / 4, 256, 0, stream>>>(latent, mean, pathidx, textlen, mellen, rowsum, T, S, C);

  k_batch<<<B, 256, 0, stream>>>(rowsum, pathidx, logdur, textlen, mellen, nllc, durc, T, S, C);

  k_final<<<1, 64, 0, stream>>>(nllc, durc, out, B);
}

// Round 8
// 351.443 us; speedup vs baseline: 1.9880x; 1.0745x over previous
//
#include <hip/hip_runtime.h>
#include <math.h>

#define LOG2PI 1.8378770664093453f
#define F32MIN (-3.4028234663852886e38f)
#define SMAX 384       // S (lane math assumes 384 = 64 lanes * 6 cols)
#define NW 38          // direction words per column = ceil(1200/32)

// ---------------------------------------------------------------------------
// Kernel 1: row sums of squares  lx2[b,t] = sum_c latent^2, lm2[b,s] = sum_c mean^2
__global__ __launch_bounds__(64) void k_sums(
    const float* __restrict__ latent, const float* __restrict__ mean,
    float* __restrict__ lx2, float* __restrict__ lm2, int BT, int BS, int C) {
  int row = blockIdx.x;
  int lane = threadIdx.x;
  const float* src;
  float* dst;
  if (row < BT) { src = latent + (size_t)row * C; dst = lx2 + row; }
  else          { src = mean + (size_t)(row - BT) * C; dst = lm2 + (row - BT); }
  float s = 0.f;
  for (int c = lane; c < C; c += 64) { float v = src[c]; s += v * v; }
  #pragma unroll
  for (int off = 32; off; off >>= 1) s += __shfl_down(s, off);
  if (lane == 0) *dst = s;
}

// ---------------------------------------------------------------------------
// Kernel 2: ll[b,t,s] = -0.5*(LOG2PI + lx2 - 2*dot + lm2) * attnmask
__global__ __launch_bounds__(256) void k_scores(
    const float* __restrict__ latent, const float* __restrict__ mean,
    const float* __restrict__ lx2, const float* __restrict__ lm2,
    const int* __restrict__ textlen, const int* __restrict__ mellen,
    float* __restrict__ ll, int T, int S, int C) {
  int b  = blockIdx.z;
  int t0 = blockIdx.x * 64;
  int s0 = blockIdx.y * 64;
  int mel = mellen[b], txt = textlen[b];
  int tid = threadIdx.x;
  int ty = tid >> 4, tx = tid & 15;
  float* out = ll + ((size_t)b * T + t0) * S + s0;

  if (t0 >= mel || s0 >= txt) {
    float4 z = make_float4(0.f, 0.f, 0.f, 0.f);
    #pragma unroll
    for (int i = 0; i < 4; ++i) {
      int tl = ty * 4 + i;
      if (t0 + tl < T) *(float4*)(out + (size_t)tl * S + tx * 4) = z;
    }
    return;
  }

  __shared__ float At[16][64];
  __shared__ float Bt[16][64];
  float acc[4][4] = {};

  const float* Ab = latent + ((size_t)b * T + t0) * C;
  const float* Bb = mean + ((size_t)b * S + s0) * C;

  for (int kk = 0; kk < C; kk += 16) {
    int r  = tid >> 2;
    int cg = tid & 3;
    float4 a = (t0 + r < T) ? *(const float4*)(Ab + (size_t)r * C + kk + cg * 4)
                            : make_float4(0.f, 0.f, 0.f, 0.f);
    float4 bm = *(const float4*)(Bb + (size_t)r * C + kk + cg * 4);
    At[cg * 4 + 0][r] = a.x;  At[cg * 4 + 1][r] = a.y;
    At[cg * 4 + 2][r] = a.z;  At[cg * 4 + 3][r] = a.w;
    Bt[cg * 4 + 0][r] = bm.x; Bt[cg * 4 + 1][r] = bm.y;
    Bt[cg * 4 + 2][r] = bm.z; Bt[cg * 4 + 3][r] = bm.w;
    __syncthreads();
    #pragma unroll
    for (int k = 0; k < 16; ++k) {
      float4 a4 = *(const float4*)&At[k][ty * 4];
      float4 b4 = *(const float4*)&Bt[k][tx * 4];
      float av[4] = {a4.x, a4.y, a4.z, a4.w};
      float bv[4] = {b4.x, b4.y, b4.z, b4.w};
      #pragma unroll
      for (int i = 0; i < 4; ++i)
        #pragma unroll
        for (int j = 0; j < 4; ++j)
          acc[i][j] = fmaf(av[i], bv[j], acc[i][j]);
    }
    __syncthreads();
  }

  #pragma unroll
  for (int i = 0; i < 4; ++i) {
    int t = t0 + ty * 4 + i;
    if (t >= T) continue;
    float lx = lx2[(size_t)b * T + t];
    float4 o;
    float* po = &o.x;
    #pragma unroll
    for (int j = 0; j < 4; ++j) {
      int s = s0 + tx * 4 + j;
      float d = lx - 2.f * acc[i][j] + lm2[(size_t)b * S + s];
      float v = -0.5f * (LOG2PI + d);
      po[j] = (t < mel && s < txt) ? v : 0.f;
    }
    *(float4*)(out + (size_t)(ty * 4 + i) * S + tx * 4) = o;
  }
}

// ---------------------------------------------------------------------------
// DPP wave_shr:1 — lane l gets lane l-1's value, lane 0 gets -inf. Pure VALU.
__device__ __forceinline__ float dpp_shr1_neginf(float x) {
  int r = __builtin_amdgcn_update_dpp(
      __float_as_int(-INFINITY), __float_as_int(x),
      0x138 /*wave_shr:1*/, 0xf, 0xf, false);
  return __int_as_float(r);
}

// One MAS step: pure VALU. r (bit index) is always a compile-time literal.
template <bool MASKED>
__device__ __forceinline__ void mas_step(
    int t, int sbase, int r, const float4 ab, const float2 cc,
    float& p0, float& p1, float& p2, float& p3, float& p4, float& p5,
    unsigned& a0, unsigned& a1, unsigned& a2, unsigned& a3, unsigned& a4,
    unsigned& a5) {
  float l0 = ab.x, l1 = ab.y, l2 = ab.z, l3 = ab.w, l4 = cc.x, l5 = cc.y;
  float pm1 = dpp_shr1_neginf(p5);
  bool c0 = p0 >= pm1, c1 = p1 >= p0, c2 = p2 >= p1;
  bool c3 = p3 >= p2,  c4 = p4 >= p3, c5 = p5 >= p4;
  float m0 = c0 ? p0 : pm1, m1 = c1 ? p1 : p0, m2 = c2 ? p2 : p1;
  float m3 = c3 ? p3 : p2,  m4 = c4 ? p4 : p3, m5 = c5 ? p5 : p4;
  a0 |= (unsigned)c0 << r; a1 |= (unsigned)c1 << r; a2 |= (unsigned)c2 << r;
  a3 |= (unsigned)c3 << r; a4 |= (unsigned)c4 << r; a5 |= (unsigned)c5 << r;
  if (MASKED) {
    p0 = (sbase + 0 <= t) ? m0 + l0 : F32MIN;
    p1 = (sbase + 1 <= t) ? m1 + l1 : F32MIN;
    p2 = (sbase + 2 <= t) ? m2 + l2 : F32MIN;
    p3 = (sbase + 3 <= t) ? m3 + l3 : F32MIN;
    p4 = (sbase + 4 <= t) ? m4 + l4 : F32MIN;
    p5 = (sbase + 5 <= t) ? m5 + l5 : F32MIN;
  } else {
    p0 = m0 + l0; p1 = m1 + l1; p2 = m2 + l2;
    p3 = m3 + l3; p4 = m4 + l4; p5 = m5 + l5;
  }
}

// Load ROWS rows of this lane's 6 columns into a named register buffer.
// Plain C++ loads: the compiler tracks them and inserts correct (counted or
// drain) waitcnts — consumption is a full chunk later, so even a vmcnt(0)
// drain at the next chunk boundary is ~900cy/32 steps = 28cy/step amortized.
template <int ROWS>
__device__ __forceinline__ void load_chunk_reg(
    float4 (&b4)[32], float2 (&b2)[32],
    const float* __restrict__ llb, int t0, int sbase) {
  #pragma unroll
  for (int r = 0; r < ROWS; ++r) {
    const float* p = llb + (size_t)(t0 + r) * SMAX + sbase;
    b4[r] = *(const float4*)p;
    b2[r] = *(const float2*)(p + 4);
  }
}

// Scan ROWS steps from a named register buffer; flush 6 direction words.
template <bool MASKED, int ROWS>
__device__ __forceinline__ void scan_chunk_reg(
    const float4 (&b4)[32], const float2 (&b2)[32], int cw, int sbase,
    float& p0, float& p1, float& p2, float& p3, float& p4, float& p5,
    unsigned* __restrict__ dirT) {
  unsigned a0 = 0, a1 = 0, a2 = 0, a3 = 0, a4 = 0, a5 = 0;
  int t0 = cw * 32;
  #pragma unroll
  for (int r = 0; r < ROWS; ++r) {
    mas_step<MASKED>(t0 + r, sbase, r, b4[r], b2[r],
                     p0, p1, p2, p3, p4, p5, a0, a1, a2, a3, a4, a5);
  }
  unsigned* dcol = dirT + (unsigned)sbase * NW + cw;
  dcol[0] = a0; dcol[NW] = a1; dcol[2 * NW] = a2;
  dcol[3 * NW] = a3; dcol[4 * NW] = a4; dcol[5 * NW] = a5;
}

// ---------------------------------------------------------------------------
// Kernel 3: MAS forward scan + backtrack. ONE WAVE per batch.
// Forward: double-buffered 32-row register chunks (named bufA/bufB, static
// indices only). Issue chunk c+1's 64 coalesced loads, then scan chunk c —
// prefetch distance = one full chunk, so compiler-inserted waits are amortized.
// Direction bits packed per-lane into u32 accumulators, one 6-word LDS flush
// per chunk into column-major dirT. Backtrack: R5's verified reload-flag loop.
// Assumes S == 384, T == 1200 (37 full chunks + 16-row tail; 12 masked).
__global__ __launch_bounds__(64, 1) void k_scan(
    const float* __restrict__ ll, const int* __restrict__ textlen,
    const int* __restrict__ mellen, int* __restrict__ pathidx, int T, int S) {
  int b = blockIdx.x;
  int lane = threadIdx.x;
  __shared__ unsigned dirT[SMAX * NW];      // 58368 B, column-major bit-pack

  const float* llb = ll + (size_t)b * T * S;
  int mel = mellen[b], txt = textlen[b];
  int sbase = lane * 6;
  float p0 = 0.f, p1 = 0.f, p2 = 0.f, p3 = 0.f, p4 = 0.f, p5 = 0.f;

  float4 bufA4[32], bufB4[32];
  float2 bufA2[32], bufB2[32];

  load_chunk_reg<32>(bufA4, bufA2, llb, 0, sbase);

  // masked region: chunks 0..11 (t <= 383), pair-unrolled for named buffers
  for (int c = 0; c < 12; c += 2) {
    load_chunk_reg<32>(bufB4, bufB2, llb, (c + 1) * 32, sbase);
    scan_chunk_reg<true, 32>(bufA4, bufA2, c, sbase, p0, p1, p2, p3, p4, p5, dirT);
    load_chunk_reg<32>(bufA4, bufA2, llb, (c + 2) * 32, sbase);
    scan_chunk_reg<true, 32>(bufB4, bufB2, c + 1, sbase, p0, p1, p2, p3, p4, p5, dirT);
  }
  // unmasked region: chunks 12..35
  for (int c = 12; c < 36; c += 2) {
    load_chunk_reg<32>(bufB4, bufB2, llb, (c + 1) * 32, sbase);
    scan_chunk_reg<false, 32>(bufA4, bufA2, c, sbase, p0, p1, p2, p3, p4, p5, dirT);
    load_chunk_reg<32>(bufA4, bufA2, llb, (c + 2) * 32, sbase);
    scan_chunk_reg<false, 32>(bufB4, bufB2, c + 1, sbase, p0, p1, p2, p3, p4, p5, dirT);
  }
  // chunk 36 (full) + chunk 37 (16-row tail)
  load_chunk_reg<16>(bufB4, bufB2, llb, 37 * 32, sbase);
  scan_chunk_reg<false, 32>(bufA4, bufA2, 36, sbase, p0, p1, p2, p3, p4, p5, dirT);
  scan_chunk_reg<false, 16>(bufB4, bufB2, 37, sbase, p0, p1, p2, p3, p4, p5, dirT);

  size_t base = (size_t)b * T;
  int k0 = T - mel;  // rows j >= mel: direction forced to 1, i stays txt-1
  for (int k = lane; k < k0; k += 64) pathidx[base + k] = txt - 1;

  if (lane == 0) {
    // R5's verified backtrack: reload cached word only when the path moved
    // (d==0) or j crossed a 32-row word boundary.
    int i = txt - 1;
    int j = mel - 1;
    unsigned w = ~0u;
    bool reload = true;
    for (int k = k0; k < T; ++k) {
      pathidx[base + k] = i;
      if (reload) {
        int ii = (i < 0) ? i + S : i;   // JAX negative-index wrap
        ii = (ii < 0) ? 0 : ii;
        w = (ii < txt) ? dirT[ii * NW + (j >> 5)] : ~0u;  // outside mask: d=1
      }
      int d = (int)((w >> (j & 31)) & 1u);
      reload = (d == 0) | ((j & 31) == 0);
      i += d - 1;
      --j;
    }
  }
}

// ---------------------------------------------------------------------------
// Kernel 4: write attn = one_hot(path) * attnmask (overwrites the ll scratch)
__global__ __launch_bounds__(256) void k_scatter(
    float* __restrict__ attn, const int* __restrict__ pathidx,
    const int* __restrict__ textlen, const int* __restrict__ mellen,
    int B, int T, int S) {
  size_t idx = ((size_t)blockIdx.x * blockDim.x + threadIdx.x) * 4;
  size_t total = (size_t)B * T * S;
  if (idx >= total) return;
  int s = (int)(idx % S);
  size_t row = idx / S;
  int b = (int)(row / T);
  int k = (int)(row % T);
  int pi = pathidx[row];
  int mel = mellen[b], txt = textlen[b];
  float4 o = make_float4(0.f, 0.f, 0.f, 0.f);
  if (k < mel && pi >= 0 && pi < S && pi < txt && pi >= s && pi < s + 4)
    (&o.x)[pi - s] = 1.f;
  *(float4*)(attn + idx) = o;
}

// ---------------------------------------------------------------------------
// Kernel 5: rowsum[b,k] = sum_c (latent - aligned)^2 ; aligned = mean[path] or 0
__global__ __launch_bounds__(256) void k_rowloss(
    const float* __restrict__ latent, const float* __restrict__ mean,
    const int* __restrict__ pathidx, const int* __restrict__ textlen,
    const int* __restrict__ mellen, float* __restrict__ rowsum,
    int T, int S, int C) {
  int row = blockIdx.x * 4 + (threadIdx.x >> 6);
  int lane = threadIdx.x & 63;
  int b = row / T, k = row % T;
  int pi = pathidx[row];
  int mel = mellen[b], txt = textlen[b];
  bool on = (k < mel) && (pi >= 0) && (pi < S) && (pi < txt);
  const float* L = latent + (size_t)row * C;
  const float* M = mean + ((size_t)b * S + (on ? pi : 0)) * C;
  float s = 0.f;
  for (int c = lane; c < C; c += 64) {
    float d = L[c] - (on ? M[c] : 0.f);
    s += d * d;
  }
  #pragma unroll
  for (int off = 32; off; off >>= 1) s += __shfl_down(s, off);
  if (lane == 0) rowsum[row] = s;
}

// ---------------------------------------------------------------------------
// Kernel 6: per-batch durloss (histogram + log) and nll reduction
__global__ __launch_bounds__(256) void k_batch(
    const float* __restrict__ rowsum, const int* __restrict__ pathidx,
    const float* __restrict__ logdur, const int* __restrict__ textlen,
    const int* __restrict__ mellen, float* __restrict__ nllc,
    float* __restrict__ durc, int T, int S, int C) {
  int b = blockIdx.x;
  int tid = threadIdx.x;
  __shared__ int hist[512];
  __shared__ float red[256];
  int mel = mellen[b], txt = textlen[b];
  for (int s = tid; s < S; s += 256) hist[s] = 0;
  __syncthreads();
  for (int k = tid; k < T; k += 256) {
    int pi = pathidx[(size_t)b * T + k];
    if (k < mel && pi >= 0 && pi < S && pi < txt) atomicAdd(&hist[pi], 1);
  }
  __syncthreads();
  float part = 0.f;
  for (int s = tid; s < S; s += 256) {
    float cnt = (float)hist[s];
    float gt = logf(fmaxf(cnt, 1e-5f));
    gt = (s < txt) ? gt : 0.f;
    float d = logdur[(size_t)b * S + s] - gt;
    part += d * d;
  }
  red[tid] = part; __syncthreads();
  #pragma unroll
  for (int off = 128; off; off >>= 1) {
    if (tid < off) red[tid] += red[tid + off];
    __syncthreads();
  }
  if (tid == 0) durc[b] = red[0] / (float)mel;
  __syncthreads();
  part = 0.f;
  for (int k = tid; k < T; k += 256) part += rowsum[(size_t)b * T + k];
  red[tid] = part; __syncthreads();
  #pragma unroll
  for (int off = 128; off; off >>= 1) {
    if (tid < off) red[tid] += red[tid + off];
    __syncthreads();
  }
  if (tid == 0) nllc[b] = 0.5f * (LOG2PI + red[0]) / ((float)mel * (float)C);
}

// ---------------------------------------------------------------------------
// Kernel 7: loss = mean(nllc) + mean(durc)
__global__ __launch_bounds__(64) void k_final(
    const float* __restrict__ nllc, const float* __restrict__ durc,
    float* __restrict__ out, int B) {
  int lane = threadIdx.x;
  float v = (lane < B) ? (nllc[lane] + durc[lane]) : 0.f;
  #pragma unroll
  for (int off = 32; off; off >>= 1) v += __shfl_down(v, off);
  if (lane == 0) out[0] = v / (float)B;
}

// ---------------------------------------------------------------------------
extern "C" void kernel_launch(void* const* d_in, const int* in_sizes, int n_in,
                              void* d_out, int out_size, void* d_ws, size_t ws_size,
                              hipStream_t stream) {
  (void)n_in; (void)out_size; (void)ws_size;
  const float* latent = (const float*)d_in[0];
  const float* mean   = (const float*)d_in[1];
  const float* logdur = (const float*)d_in[2];
  const int*   textlen = (const int*)d_in[3];
  const int*   mellen  = (const int*)d_in[4];

  int B = in_sizes[3];
  int S = in_sizes[2] / B;
  int C = in_sizes[1] / (B * S);
  int T = in_sizes[0] / (B * C);

  float* out = (float*)d_out;
  float* ll = out + 1;  // reuse attn region [B*T*S] as ll scratch, overwritten later

  char* ws = (char*)d_ws;
  float* lx2    = (float*)ws;            // B*T
  float* lm2    = lx2 + (size_t)B * T;   // B*S
  int*   pathidx = (int*)(lm2 + (size_t)B * S);          // B*T
  float* rowsum  = (float*)(pathidx + (size_t)B * T);    // B*T
  float* nllc    = rowsum + (size_t)B * T;               // B
  float* durc    = nllc + B;                             // B

  k_sums<<<B * T + B * S, 64, 0, stream>>>(latent, mean, lx2, lm2, B * T, B * S, C);

  dim3 g2((T + 63) / 64, (S + 63) / 64, B);
  k_scores<<<g2, 256, 0, stream>>>(latent, mean, lx2, lm2, textlen, mellen, ll, T, S, C);

  k_scan<<<B, 64, 0, stream>>>(ll, textlen, mellen, pathidx, T, S);

  size_t total = (size_t)B * T * S;
  k_scatter<<<(int)((total / 4 + 255) / 256), 256, 0, stream>>>(ll, pathidx, textlen, mellen, B, T, S);

  k_rowloss<<<(B * T) / 4, 256, 0, stream>>>(latent, mean, pathidx, textlen, mellen, rowsum, T, S, C);

  k_batch<<<B, 256, 0, stream>>>(rowsum, pathidx, logdur, textlen, mellen, nllc, durc, T, S, C);

  k_final<<<1, 64, 0, stream>>>(nllc, durc, out, B);
}

// Round 9
// 324.875 us; speedup vs baseline: 2.1506x; 1.0818x over previous
//
#include <hip/hip_runtime.h>
#include <math.h>

#define LOG2PI 1.8378770664093453f
#define F32MIN (-3.4028234663852886e38f)
#define SMAX 384       // S (lane math assumes 384 = 64 lanes * 6 cols)
#define NW 38          // direction words per column = ceil(1200/32)

// ---------------------------------------------------------------------------
// Kernel 1: row sums of squares  lx2[b,t] = sum_c latent^2, lm2[b,s] = sum_c mean^2
__global__ __launch_bounds__(64) void k_sums(
    const float* __restrict__ latent, const float* __restrict__ mean,
    float* __restrict__ lx2, float* __restrict__ lm2, int BT, int BS, int C) {
  int row = blockIdx.x;
  int lane = threadIdx.x;
  const float* src;
  float* dst;
  if (row < BT) { src = latent + (size_t)row * C; dst = lx2 + row; }
  else          { src = mean + (size_t)(row - BT) * C; dst = lm2 + (row - BT); }
  float s = 0.f;
  for (int c = lane; c < C; c += 64) { float v = src[c]; s += v * v; }
  #pragma unroll
  for (int off = 32; off; off >>= 1) s += __shfl_down(s, off);
  if (lane == 0) *dst = s;
}

// ---------------------------------------------------------------------------
// Kernel 2: ll[b,t,s] = -0.5*(LOG2PI + lx2 - 2*dot + lm2) * attnmask
__global__ __launch_bounds__(256) void k_scores(
    const float* __restrict__ latent, const float* __restrict__ mean,
    const float* __restrict__ lx2, const float* __restrict__ lm2,
    const int* __restrict__ textlen, const int* __restrict__ mellen,
    float* __restrict__ ll, int T, int S, int C) {
  int b  = blockIdx.z;
  int t0 = blockIdx.x * 64;
  int s0 = blockIdx.y * 64;
  int mel = mellen[b], txt = textlen[b];
  int tid = threadIdx.x;
  int ty = tid >> 4, tx = tid & 15;
  float* out = ll + ((size_t)b * T + t0) * S + s0;

  if (t0 >= mel || s0 >= txt) {
    float4 z = make_float4(0.f, 0.f, 0.f, 0.f);
    #pragma unroll
    for (int i = 0; i < 4; ++i) {
      int tl = ty * 4 + i;
      if (t0 + tl < T) *(float4*)(out + (size_t)tl * S + tx * 4) = z;
    }
    return;
  }

  __shared__ float At[16][64];
  __shared__ float Bt[16][64];
  float acc[4][4] = {};

  const float* Ab = latent + ((size_t)b * T + t0) * C;
  const float* Bb = mean + ((size_t)b * S + s0) * C;

  for (int kk = 0; kk < C; kk += 16) {
    int r  = tid >> 2;
    int cg = tid & 3;
    float4 a = (t0 + r < T) ? *(const float4*)(Ab + (size_t)r * C + kk + cg * 4)
                            : make_float4(0.f, 0.f, 0.f, 0.f);
    float4 bm = *(const float4*)(Bb + (size_t)r * C + kk + cg * 4);
    At[cg * 4 + 0][r] = a.x;  At[cg * 4 + 1][r] = a.y;
    At[cg * 4 + 2][r] = a.z;  At[cg * 4 + 3][r] = a.w;
    Bt[cg * 4 + 0][r] = bm.x; Bt[cg * 4 + 1][r] = bm.y;
    Bt[cg * 4 + 2][r] = bm.z; Bt[cg * 4 + 3][r] = bm.w;
    __syncthreads();
    #pragma unroll
    for (int k = 0; k < 16; ++k) {
      float4 a4 = *(const float4*)&At[k][ty * 4];
      float4 b4 = *(const float4*)&Bt[k][tx * 4];
      float av[4] = {a4.x, a4.y, a4.z, a4.w};
      float bv[4] = {b4.x, b4.y, b4.z, b4.w};
      #pragma unroll
      for (int i = 0; i < 4; ++i)
        #pragma unroll
        for (int j = 0; j < 4; ++j)
          acc[i][j] = fmaf(av[i], bv[j], acc[i][j]);
    }
    __syncthreads();
  }

  #pragma unroll
  for (int i = 0; i < 4; ++i) {
    int t = t0 + ty * 4 + i;
    if (t >= T) continue;
    float lx = lx2[(size_t)b * T + t];
    float4 o;
    float* po = &o.x;
    #pragma unroll
    for (int j = 0; j < 4; ++j) {
      int s = s0 + tx * 4 + j;
      float d = lx - 2.f * acc[i][j] + lm2[(size_t)b * S + s];
      float v = -0.5f * (LOG2PI + d);
      po[j] = (t < mel && s < txt) ? v : 0.f;
    }
    *(float4*)(out + (size_t)(ty * 4 + i) * S + tx * 4) = o;
  }
}

// ---------------------------------------------------------------------------
// DPP wave_shr:1 — lane l gets lane l-1's value, lane 0 gets -inf. Pure VALU.
__device__ __forceinline__ float dpp_shr1_neginf(float x) {
  int r = __builtin_amdgcn_update_dpp(
      __float_as_int(-INFINITY), __float_as_int(x),
      0x138 /*wave_shr:1*/, 0xf, 0xf, false);
  return __int_as_float(r);
}

// One MAS step: pure VALU. r (bit index) is wave-uniform (may be runtime).
template <bool MASKED>
__device__ __forceinline__ void mas_step(
    int t, int sbase, int r, const float2 A0, const float2 A1, const float2 A2,
    float& p0, float& p1, float& p2, float& p3, float& p4, float& p5,
    unsigned& a0, unsigned& a1, unsigned& a2, unsigned& a3, unsigned& a4,
    unsigned& a5) {
  float l0 = A0.x, l1 = A0.y, l2 = A1.x, l3 = A1.y, l4 = A2.x, l5 = A2.y;
  float pm1 = dpp_shr1_neginf(p5);
  bool c0 = p0 >= pm1, c1 = p1 >= p0, c2 = p2 >= p1;
  bool c3 = p3 >= p2,  c4 = p4 >= p3, c5 = p5 >= p4;
  float m0 = c0 ? p0 : pm1, m1 = c1 ? p1 : p0, m2 = c2 ? p2 : p1;
  float m3 = c3 ? p3 : p2,  m4 = c4 ? p4 : p3, m5 = c5 ? p5 : p4;
  a0 |= (unsigned)c0 << r; a1 |= (unsigned)c1 << r; a2 |= (unsigned)c2 << r;
  a3 |= (unsigned)c3 << r; a4 |= (unsigned)c4 << r; a5 |= (unsigned)c5 << r;
  if (MASKED) {
    p0 = (sbase + 0 <= t) ? m0 + l0 : F32MIN;
    p1 = (sbase + 1 <= t) ? m1 + l1 : F32MIN;
    p2 = (sbase + 2 <= t) ? m2 + l2 : F32MIN;
    p3 = (sbase + 3 <= t) ? m3 + l3 : F32MIN;
    p4 = (sbase + 4 <= t) ? m4 + l4 : F32MIN;
    p5 = (sbase + 5 <= t) ? m5 + l5 : F32MIN;
  } else {
    p0 = m0 + l0; p1 = m1 + l1; p2 = m2 + l2;
    p3 = m3 + l3; p4 = m4 + l4; p5 = m5 + l5;
  }
}

// ---------------------------------------------------------------------------
// Consumer: scan ROWS steps of one LDS chunk with a COMPACT ROLLED loop
// (2 steps/iter, named A/B float2 regs — no arrays, no giant unroll).
// B-row reads issue one step before use; the loop body is ~70 instructions
// so it lives in I-cache and the compiler can emit counted lgkmcnt.
template <bool MASKED, int ROWS>
__device__ __forceinline__ void scan_chunk_lds(
    const float* __restrict__ rcur, int t0, int sbase,
    float& p0, float& p1, float& p2, float& p3, float& p4, float& p5,
    unsigned* __restrict__ dirT, int cw) {
  unsigned a0 = 0, a1 = 0, a2 = 0, a3 = 0, a4 = 0, a5 = 0;
  const float2* q = (const float2*)(rcur + sbase);   // row stride = 192 float2
  float2 A0 = q[0], A1 = q[1], A2 = q[2];
  #pragma unroll 1
  for (int r = 0; r < ROWS; r += 2) {
    const float2* qb = q + (size_t)(r + 1) * 192;
    float2 B0 = qb[0], B1 = qb[1], B2 = qb[2];
    mas_step<MASKED>(t0 + r, sbase, r, A0, A1, A2,
                     p0, p1, p2, p3, p4, p5, a0, a1, a2, a3, a4, a5);
    int rn = (r + 2 < ROWS) ? (r + 2) : (ROWS - 1);   // clamp: dummy in-bounds read
    const float2* qa = q + (size_t)rn * 192;
    A0 = qa[0]; A1 = qa[1]; A2 = qa[2];
    mas_step<MASKED>(t0 + r + 1, sbase, r + 1, B0, B1, B2,
                     p0, p1, p2, p3, p4, p5, a0, a1, a2, a3, a4, a5);
  }
  unsigned* dcol = dirT + (unsigned)sbase * NW + cw;
  dcol[0] = a0; dcol[NW] = a1; dcol[2 * NW] = a2;
  dcol[3 * NW] = a3; dcol[4 * NW] = a4; dcol[5 * NW] = a5;
}

// ---------------------------------------------------------------------------
// Kernel 3: MAS forward scan + backtrack. One block (4 waves) per batch.
// Wave 0: compact rolled scan loop from LDS. Waves 1-3: double-buffer the
// next 32-row ll chunk global->reg->LDS (proven to keep up in R4/R5).
// Direction bits packed per-lane into u32 accumulators, one 6-word LDS flush
// per chunk into column-major dirT. Backtrack: R5/R8's verified loop.
// Assumes S == 384, T == 37*32 + 16.
__global__ __launch_bounds__(256, 1) void k_scan(
    const float* __restrict__ ll, const int* __restrict__ textlen,
    const int* __restrict__ mellen, int* __restrict__ pathidx, int T, int S) {
  int b = blockIdx.x;
  int tid = threadIdx.x;
  int lane = tid & 63;
  __shared__ float rows[2][32][SMAX];       // 98304 B
  __shared__ unsigned dirT[SMAX * NW];      // 58368 B, column-major bit-pack

  const float* llb = ll + (size_t)b * T * S;
  int mel = mellen[b], txt = textlen[b];
  int sbase = lane * 6;
  int nfull = T / 32;                        // 37
  int nch = (T + 31) / 32;                   // 38 (16-row tail)
  float p0 = 0.f, p1 = 0.f, p2 = 0.f, p3 = 0.f, p4 = 0.f, p5 = 0.f;

  // prologue: loader waves fill chunk 0 (32*384 floats = 3072 float4, 192x16)
  if (tid >= 64) {
    int lid = tid - 64;
    const float4* g = (const float4*)llb;
    float4* d = (float4*)&rows[0][0][0];
    #pragma unroll
    for (int k = 0; k < 16; ++k) d[k * 192 + lid] = g[k * 192 + lid];
  }
  __syncthreads();

  for (int c = 0; c < nch; ++c) {
    if (tid >= 64) {
      int nxt = c + 1;
      if (nxt < nch) {
        int lid = tid - 64;
        const float4* g = (const float4*)(llb + (size_t)nxt * 32 * S);
        float4* d = (float4*)&rows[nxt & 1][0][0];
        if (nxt < nfull) {
          float4 stg[16];
          #pragma unroll
          for (int k = 0; k < 16; ++k) stg[k] = g[k * 192 + lid];
          #pragma unroll
          for (int k = 0; k < 16; ++k) d[k * 192 + lid] = stg[k];
        } else {
          float4 stg[8];
          #pragma unroll
          for (int k = 0; k < 8; ++k) stg[k] = g[k * 192 + lid];
          #pragma unroll
          for (int k = 0; k < 8; ++k) d[k * 192 + lid] = stg[k];
        }
      }
    } else {
      const float* rc = &rows[c & 1][0][0];
      int t0 = c * 32;
      if (c < nfull) {
        if (t0 < S)   // s<=t masking only relevant while t can be < s_max
          scan_chunk_lds<true, 32>(rc, t0, sbase, p0, p1, p2, p3, p4, p5, dirT, c);
        else
          scan_chunk_lds<false, 32>(rc, t0, sbase, p0, p1, p2, p3, p4, p5, dirT, c);
      } else {
        scan_chunk_lds<false, 16>(rc, t0, sbase, p0, p1, p2, p3, p4, p5, dirT, c);
      }
    }
    __syncthreads();
  }

  if (tid >= 64) return;

  size_t base = (size_t)b * T;
  int k0 = T - mel;  // rows j >= mel: direction forced to 1, i stays txt-1
  for (int k = lane; k < k0; k += 64) pathidx[base + k] = txt - 1;

  if (lane == 0) {
    // Verified backtrack (R5/R8): reload cached word only when the path moved
    // (d==0) or j crossed a 32-row word boundary.
    int i = txt - 1;
    int j = mel - 1;
    unsigned w = ~0u;
    bool reload = true;
    for (int k = k0; k < T; ++k) {
      pathidx[base + k] = i;
      if (reload) {
        int ii = (i < 0) ? i + S : i;   // JAX negative-index wrap
        ii = (ii < 0) ? 0 : ii;
        w = (ii < txt) ? dirT[ii * NW + (j >> 5)] : ~0u;  // outside mask: d=1
      }
      int d = (int)((w >> (j & 31)) & 1u);
      reload = (d == 0) | ((j & 31) == 0);
      i += d - 1;
      --j;
    }
  }
}

// ---------------------------------------------------------------------------
// Kernel 4: write attn = one_hot(path) * attnmask (overwrites the ll scratch)
__global__ __launch_bounds__(256) void k_scatter(
    float* __restrict__ attn, const int* __restrict__ pathidx,
    const int* __restrict__ textlen, const int* __restrict__ mellen,
    int B, int T, int S) {
  size_t idx = ((size_t)blockIdx.x * blockDim.x + threadIdx.x) * 4;
  size_t total = (size_t)B * T * S;
  if (idx >= total) return;
  int s = (int)(idx % S);
  size_t row = idx / S;
  int b = (int)(row / T);
  int k = (int)(row % T);
  int pi = pathidx[row];
  int mel = mellen[b], txt = textlen[b];
  float4 o = make_float4(0.f, 0.f, 0.f, 0.f);
  if (k < mel && pi >= 0 && pi < S && pi < txt && pi >= s && pi < s + 4)
    (&o.x)[pi - s] = 1.f;
  *(float4*)(attn + idx) = o;
}

// ---------------------------------------------------------------------------
// Kernel 5: rowsum[b,k] = sum_c (latent - aligned)^2 ; aligned = mean[path] or 0
__global__ __launch_bounds__(256) void k_rowloss(
    const float* __restrict__ latent, const float* __restrict__ mean,
    const int* __restrict__ pathidx, const int* __restrict__ textlen,
    const int* __restrict__ mellen, float* __restrict__ rowsum,
    int T, int S, int C) {
  int row = blockIdx.x * 4 + (threadIdx.x >> 6);
  int lane = threadIdx.x & 63;
  int b = row / T, k = row % T;
  int pi = pathidx[row];
  int mel = mellen[b], txt = textlen[b];
  bool on = (k < mel) && (pi >= 0) && (pi < S) && (pi < txt);
  const float* L = latent + (size_t)row * C;
  const float* M = mean + ((size_t)b * S + (on ? pi : 0)) * C;
  float s = 0.f;
  for (int c = lane; c < C; c += 64) {
    float d = L[c] - (on ? M[c] : 0.f);
    s += d * d;
  }
  #pragma unroll
  for (int off = 32; off; off >>= 1) s += __shfl_down(s, off);
  if (lane == 0) rowsum[row] = s;
}

// ---------------------------------------------------------------------------
// Kernel 6: per-batch durloss (histogram + log) and nll reduction
__global__ __launch_bounds__(256) void k_batch(
    const float* __restrict__ rowsum, const int* __restrict__ pathidx,
    const float* __restrict__ logdur, const int* __restrict__ textlen,
    const int* __restrict__ mellen, float* __restrict__ nllc,
    float* __restrict__ durc, int T, int S, int C) {
  int b = blockIdx.x;
  int tid = threadIdx.x;
  __shared__ int hist[512];
  __shared__ float red[256];
  int mel = mellen[b], txt = textlen[b];
  for (int s = tid; s < S; s += 256) hist[s] = 0;
  __syncthreads();
  for (int k = tid; k < T; k += 256) {
    int pi = pathidx[(size_t)b * T + k];
    if (k < mel && pi >= 0 && pi < S && pi < txt) atomicAdd(&hist[pi], 1);
  }
  __syncthreads();
  float part = 0.f;
  for (int s = tid; s < S; s += 256) {
    float cnt = (float)hist[s];
    float gt = logf(fmaxf(cnt, 1e-5f));
    gt = (s < txt) ? gt : 0.f;
    float d = logdur[(size_t)b * S + s] - gt;
    part += d * d;
  }
  red[tid] = part; __syncthreads();
  #pragma unroll
  for (int off = 128; off; off >>= 1) {
    if (tid < off) red[tid] += red[tid + off];
    __syncthreads();
  }
  if (tid == 0) durc[b] = red[0] / (float)mel;
  __syncthreads();
  part = 0.f;
  for (int k = tid; k < T; k += 256) part += rowsum[(size_t)b * T + k];
  red[tid] = part; __syncthreads();
  #pragma unroll
  for (int off = 128; off; off >>= 1) {
    if (tid < off) red[tid] += red[tid + off];
    __syncthreads();
  }
  if (tid == 0) nllc[b] = 0.5f * (LOG2PI + red[0]) / ((float)mel * (float)C);
}

// ---------------------------------------------------------------------------
// Kernel 7: loss = mean(nllc) + mean(durc)
__global__ __launch_bounds__(64) void k_final(
    const float* __restrict__ nllc, const float* __restrict__ durc,
    float* __restrict__ out, int B) {
  int lane = threadIdx.x;
  float v = (lane < B) ? (nllc[lane] + durc[lane]) : 0.f;
  #pragma unroll
  for (int off = 32; off; off >>= 1) v += __shfl_down(v, off);
  if (lane == 0) out[0] = v / (float)B;
}

// ---------------------------------------------------------------------------
extern "C" void kernel_launch(void* const* d_in, const int* in_sizes, int n_in,
                              void* d_out, int out_size, void* d_ws, size_t ws_size,
                              hipStream_t stream) {
  (void)n_in; (void)out_size; (void)ws_size;
  const float* latent = (const float*)d_in[0];
  const float* mean   = (const float*)d_in[1];
  const float* logdur = (const float*)d_in[2];
  const int*   textlen = (const int*)d_in[3];
  const int*   mellen  = (const int*)d_in[4];

  int B = in_sizes[3];
  int S = in_sizes[2] / B;
  int C = in_sizes[1] / (B * S);
  int T = in_sizes[0] / (B * C);

  float* out = (float*)d_out;
  float* ll = out + 1;  // reuse attn region [B*T*S] as ll scratch, overwritten later

  char* ws = (char*)d_ws;
  float* lx2    = (float*)ws;            // B*T
  float* lm2    = lx2 + (size_t)B * T;   // B*S
  int*   pathidx = (int*)(lm2 + (size_t)B * S);          // B*T
  float* rowsum  = (float*)(pathidx + (size_t)B * T);    // B*T
  float* nllc    = rowsum + (size_t)B * T;               // B
  float* durc    = nllc + B;                             // B

  k_sums<<<B * T + B * S, 64, 0, stream>>>(latent, mean, lx2, lm2, B * T, B * S, C);

  dim3 g2((T + 63) / 64, (S + 63) / 64, B);
  k_scores<<<g2, 256, 0, stream>>>(latent, mean, lx2, lm2, textlen, mellen, ll, T, S, C);

  k_scan<<<B, 256, 0, stream>>>(ll, textlen, mellen, pathidx, T, S);

  size_t total = (size_t)B * T * S;
  k_scatter<<<(int)((total / 4 + 255) / 256), 256, 0, stream>>>(ll, pathidx, textlen, mellen, B, T, S);

  k_rowloss<<<(B * T) / 4, 256, 0, stream>>>(latent, mean, pathidx, textlen, mellen, rowsum, T, S, C);

  k_batch<<<B, 256, 0, stream>>>(rowsum, pathidx, logdur, textlen, mellen, nllc, durc, T, S, C);

  k_final<<<1, 64, 0, stream>>>(nllc, durc, out, B);
}